// Round 19
// baseline (294.512 us; speedup 1.0000x reference)
//
#include <hip/hip_runtime.h>
#include <hip/hip_bf16.h>

// Problem constants
#define B_  32
#define N_  512
#define DM_ 512
#define H_  8
#define DH_ 64
#define DI_ 2048

typedef __attribute__((ext_vector_type(8))) __bf16 bf16x8;
typedef __attribute__((ext_vector_type(4))) float f32x4;
typedef __attribute__((ext_vector_type(8))) unsigned short us8;
typedef __attribute__((ext_vector_type(4))) unsigned short us4;
typedef __attribute__((ext_vector_type(4))) unsigned int u32x4;

typedef __attribute__((address_space(1))) const void g_cvoid;
typedef __attribute__((address_space(3))) void l_void;

__device__ __forceinline__ float b2f(unsigned short u) {
  union { unsigned int i; float f; } x; x.i = ((unsigned int)u) << 16; return x.f;
}
__device__ __forceinline__ unsigned short f2b(float f) {
  union { float f; unsigned int i; } x; x.f = f;
  unsigned int r = x.i + 0x7FFFu + ((x.i >> 16) & 1u);
  return (unsigned short)(r >> 16);
}
__device__ __forceinline__ void gld_lds16(const unsigned short* g, unsigned short* l) {
  __builtin_amdgcn_global_load_lds((g_cvoid*)g, (l_void*)l, 16, 0, 0);
}
// bijective XCD swizzle for grids with nwg % 8 == 0
__device__ __forceinline__ int xcd_swz(int bid, int nwg) {
  return (bid & 7) * (nwg >> 3) + (bid >> 3);
}

// ---------------- fused prologue: prep_sm (2048 blocks) + conv_w (1536) + LN1 (4096) ----------------
__global__ __launch_bounds__(256) void fused_pre(
    const float* __restrict__ Dg, const float* __restrict__ nmg,
    const float* __restrict__ mkg, const float* __restrict__ gammaf,
    const int* __restrict__ ra, const int* __restrict__ rb,
    unsigned int* __restrict__ packed,
    const float* __restrict__ wa, const float* __restrict__ wb,
    const float* __restrict__ wc, const float* __restrict__ wd,
    unsigned short* __restrict__ oa, unsigned short* __restrict__ ob,
    unsigned short* __restrict__ oc, unsigned short* __restrict__ od,
    const float* __restrict__ x, const float* __restrict__ lw,
    const float* __restrict__ lb, unsigned short* __restrict__ y) {
  __shared__ unsigned int t[64][65];
  const int blk = blockIdx.x;
  const int tid = threadIdx.x;
  if (blk < 2048) {
    // ---- prep_sm: E=exp(nm-gamma*D), Em=E*mask, packed [b][ki][q] ----
    const int kt = blk & 7, qt = (blk >> 3) & 7, b = blk >> 6;
    const int ra_e = *ra, rb_e = *rb;
    const int r = tid >> 2;
    const int c = (tid & 3) * 16;
    const int q_g = qt * 64 + r;
    const int rq = (q_g >= ra_e) + (q_g >= rb_e);
    const float g0 = gammaf[rq * 4], g1 = gammaf[rq * 4 + 1], g2 = gammaf[rq * 4 + 2];
    const size_t base = ((size_t)b * N_ + q_g) * N_ + kt * 64 + c;
#pragma unroll
    for (int i = 0; i < 4; i++) {
      f32x4 dv = *(const f32x4*)(Dg + base + i * 4);
      f32x4 nv = *(const f32x4*)(nmg + base + i * 4);
      f32x4 mv = *(const f32x4*)(mkg + base + i * 4);
#pragma unroll
      for (int j = 0; j < 4; j++) {
        const int gk = kt * 64 + c + i * 4 + j;
        const float g = gk >= rb_e ? g2 : (gk >= ra_e ? g1 : g0);
        const float E = __expf(nv[j] - g * dv[j]);
        const float Em = E * mv[j];
        t[r][c + i * 4 + j] = (unsigned int)f2b(E) | ((unsigned int)f2b(Em) << 16);
      }
    }
    __syncthreads();
    const int rr = tid >> 2;
    const int cc = (tid & 3) * 16;
    unsigned int* dst = packed + ((size_t)b * N_ + kt * 64 + rr) * N_ + qt * 64 + cc;
#pragma unroll
    for (int i = 0; i < 4; i++) {
      u32x4 v;
#pragma unroll
      for (int j = 0; j < 4; j++) v[j] = t[cc + i * 4 + j][rr];
      *(u32x4*)(dst + i * 4) = v;
    }
  } else if (blk < 3584) {
    // ---- conv_w: f32 -> bf16 weight conversion ----
    const int bid = blk - 2048;
    const float* src; unsigned short* dst; int idx;
    if (bid < 384)       { src = wa; dst = oa; idx = bid; }
    else if (bid < 512)  { src = wb; dst = ob; idx = bid - 384; }
    else if (bid < 1024) { src = wc; dst = oc; idx = bid - 512; }
    else                 { src = wd; dst = od; idx = bid - 1024; }
    const int off = idx * 2048 + tid * 8;
    f32x4 x0 = *(const f32x4*)(src + off);
    f32x4 x1 = *(const f32x4*)(src + off + 4);
    us8 o;
#pragma unroll
    for (int i = 0; i < 4; i++) { o[i] = f2b(x0[i]); o[4 + i] = f2b(x1[i]); }
    *(us8*)(dst + off) = o;
  } else {
    // ---- LN1: f32 -> bf16, one wave per row ----
    const int row  = (blk - 3584) * 4 + (tid >> 6);
    const int lane = tid & 63;
    const float* xr = x + (size_t)row * DM_ + lane * 8;
    f32x4 x0 = *(const f32x4*)xr;
    f32x4 x1 = *(const f32x4*)(xr + 4);
    float v[8]; float s = 0.f;
#pragma unroll
    for (int i = 0; i < 4; i++) { v[i] = x0[i]; v[4 + i] = x1[i]; }
#pragma unroll
    for (int i = 0; i < 8; i++) s += v[i];
#pragma unroll
    for (int o = 1; o < 64; o <<= 1) s += __shfl_xor(s, o);
    const float mu = s * (1.f / DM_);
    float q = 0.f;
#pragma unroll
    for (int i = 0; i < 8; i++) { float d = v[i] - mu; q += d * d; }
#pragma unroll
    for (int o = 1; o < 64; o <<= 1) q += __shfl_xor(q, o);
    const float rstd = rsqrtf(q * (1.f / DM_) + 1e-5f);
    f32x4 w0 = *(const f32x4*)(lw + lane * 8);
    f32x4 w1 = *(const f32x4*)(lw + lane * 8 + 4);
    f32x4 b0 = *(const f32x4*)(lb + lane * 8);
    f32x4 b1 = *(const f32x4*)(lb + lane * 8 + 4);
    us8 out;
#pragma unroll
    for (int i = 0; i < 4; i++) {
      out[i]     = f2b((v[i] - mu) * rstd * w0[i] + b0[i]);
      out[4 + i] = f2b((v[4 + i] - mu) * rstd * w1[i] + b1[i]);
    }
    *(us8*)(y + (size_t)row * DM_ + lane * 8) = out;
  }
}

// ---------------- LayerNorm (f32 in, bf16 out): one wave per row of 512 ----------------
__global__ __launch_bounds__(256) void ln_kernel(const float* __restrict__ x,
                                                 const float* __restrict__ w,
                                                 const float* __restrict__ b,
                                                 unsigned short* __restrict__ y) {
  const int row  = blockIdx.x * 4 + (threadIdx.x >> 6);
  const int lane = threadIdx.x & 63;
  const float* xr = x + (size_t)row * DM_ + lane * 8;
  f32x4 x0 = *(const f32x4*)xr;
  f32x4 x1 = *(const f32x4*)(xr + 4);
  float v[8]; float s = 0.f;
#pragma unroll
  for (int i = 0; i < 4; i++) { v[i] = x0[i]; v[4 + i] = x1[i]; }
#pragma unroll
  for (int i = 0; i < 8; i++) s += v[i];
#pragma unroll
  for (int o = 1; o < 64; o <<= 1) s += __shfl_xor(s, o);
  const float mu = s * (1.f / DM_);
  float q = 0.f;
#pragma unroll
  for (int i = 0; i < 8; i++) { float d = v[i] - mu; q += d * d; }
#pragma unroll
  for (int o = 1; o < 64; o <<= 1) q += __shfl_xor(q, o);
  const float rstd = rsqrtf(q * (1.f / DM_) + 1e-5f);
  f32x4 w0 = *(const f32x4*)(w + lane * 8);
  f32x4 w1 = *(const f32x4*)(w + lane * 8 + 4);
  f32x4 b0 = *(const f32x4*)(b + lane * 8);
  f32x4 b1 = *(const f32x4*)(b + lane * 8 + 4);
  us8 out;
#pragma unroll
  for (int i = 0; i < 4; i++) {
    out[i]     = f2b((v[i] - mu) * rstd * w0[i] + b0[i]);
    out[4 + i] = f2b((v[4 + i] - mu) * rstd * w1[i] + b1[i]);
  }
  *(us8*)(y + (size_t)row * DM_ + lane * 8) = out;
}

// ---------------- GEMM: C = A(MxK,bf16) * B(NxK,bf16)^T, TMxTN tile, BK=32 ----------------
// 2-phase double-buffered LDS pipeline; R9-exact epilogue; 4-chunk XOR source
// swizzle (bank conflicts = 0, R14-verified).
// TM=128: 4 waves as 2x2, per-wave 64xTN/2. TM=64: 4 waves as 2x2, per-wave
// 32x32 (FFN2: grid x2 -> 8 blocks/CU, LDS 16KB, acc 16 AGPR).
struct GemmP {
  const unsigned short* A;
  const unsigned short* Bw;
  const float* bias;
  const float* residf;
  unsigned short* outb;
  float* outf;
  unsigned short* out_q;
  unsigned short* out_k;
  int K;
  int tiles_n;
  int ldo;
};

// EPI: 0=QKV scatter(bf16), 1=+resid->f32, 2=relu(+bias)->bf16, 3=+bias+resid->f32
template <int EPI, int TN, int TM>
__global__ __launch_bounds__(256) void gemm_bt(GemmP p) {
  constexpr int NFR = TN / 32;  // n-frags per wave
  constexpr int MFR = TM / 32;  // m-frags per wave
  __shared__ unsigned short As[2][TM * 32];
  __shared__ unsigned short Bs[2][TN * 32];
  const int tid = threadIdx.x;
  const int wave = tid >> 6, lane = tid & 63;
  const int wm = wave >> 1, wn = wave & 1;
  const int bid = xcd_swz(blockIdx.x, gridDim.x);
  const int tn = bid % p.tiles_n, tm = bid / p.tiles_n;
  const int K = p.K;
  const unsigned short* Ab = p.A + (size_t)tm * TM * K;
  const unsigned short* Bb = p.Bw + (size_t)tn * TN * K;
  f32x4 acc[MFR][NFR];
#pragma unroll
  for (int i = 0; i < MFR; i++)
#pragma unroll
    for (int j = 0; j < NFR; j++) acc[i][j] = (f32x4){0.f, 0.f, 0.f, 0.f};

  const int l15 = lane & 15;
  const int srow = lane >> 2;
  const int scol = (((lane & 3) ^ ((srow >> 1) & 3))) * 8;  // source-swizzled chunk
  auto stage = [&](int buf, int kt) {
#pragma unroll
    for (int i = 0; i < TM / 64; i++) {
      const int r = wave * (TM / 4) + i * 16;
      gld_lds16(Ab + (size_t)(r + srow) * K + kt + scol, &As[buf][r * 32]);
    }
    if (TN == 128) {
#pragma unroll
      for (int i = 0; i < 2; i++) {
        const int r = wave * 32 + i * 16;
        gld_lds16(Bb + (size_t)(r + srow) * K + kt + scol, &Bs[buf][r * 32]);
      }
    } else {
      const int r = wave * 16;
      gld_lds16(Bb + (size_t)(r + srow) * K + kt + scol, &Bs[buf][r * 32]);
    }
  };

  stage(0, 0);
  __syncthreads();  // buf0 ready
  const int nIter = K >> 5;
  const int rchunk = (((lane >> 4) ^ ((l15 >> 1) & 3))) * 8;  // swizzled read slot
  for (int it = 0; it < nIter; it++) {
    const int buf = it & 1;
    if (it + 1 < nIter) stage(buf ^ 1, (it + 1) * 32);  // overlap with compute
    bf16x8 af[MFR], bfr[NFR];
#pragma unroll
    for (int m = 0; m < MFR; m++)
      af[m] = *(const bf16x8*)&As[buf][(wm * (TM / 2) + m * 16 + l15) * 32 + rchunk];
#pragma unroll
    for (int n = 0; n < NFR; n++)
      bfr[n] = *(const bf16x8*)&Bs[buf][(wn * (TN / 2) + n * 16 + l15) * 32 + rchunk];
#pragma unroll
    for (int m = 0; m < MFR; m++)
#pragma unroll
      for (int n = 0; n < NFR; n++)
        acc[m][n] = __builtin_amdgcn_mfma_f32_16x16x32_bf16(af[m], bfr[n], acc[m][n], 0, 0, 0);
    __syncthreads();  // next buf staged + all waves done reading this buf
  }

  const int r0 = tm * TM + wm * (TM / 2);
  const int c0 = tn * TN + wn * (TN / 2);
#pragma unroll
  for (int m = 0; m < MFR; m++) {
#pragma unroll
    for (int n = 0; n < NFR; n++) {
#pragma unroll
      for (int rr = 0; rr < 4; rr++) {
        const int row = r0 + m * 16 + (lane >> 4) * 4 + rr;
        const int col = c0 + n * 16 + (lane & 15);
        float v = acc[m][n][rr];
        if (EPI == 0) {
          v += p.bias[col];
          const int h = col / 192, j = col % 192;
          const int bb = row >> 9, nn = row & 511;
          const size_t base = (((size_t)bb * H_ + h) * N_ + nn) * DH_;
          if (j < 64)       p.outb [base + j]        = f2b(v);            // V
          else if (j < 128) p.out_q[base + j - 64]   = f2b(v * 0.125f);   // Q (scale folded)
          else              p.out_k[base + j - 128]  = f2b(v);            // K
        } else if (EPI == 1) {
          p.outf[(size_t)row * p.ldo + col] = v + p.residf[(size_t)row * p.ldo + col];
        } else if (EPI == 2) {
          v += p.bias[col];
          v = v > 0.f ? v : 0.f;
          p.outb[(size_t)row * p.ldo + col] = f2b(v);
        } else {
          p.outf[(size_t)row * p.ldo + col] =
              v + p.bias[col] + p.residf[(size_t)row * p.ldo + col];
        }
      }
    }
  }
}

// ---------------- V transpose: V[b][h][n][d] -> Vt[b][h][d][n] (bf16) ----------------
__global__ __launch_bounds__(256) void transp_v(const unsigned short* __restrict__ V,
                                                unsigned short* __restrict__ Vt) {
  __shared__ unsigned short t[64][65];
  const int bid = blockIdx.x;
  const int bh = bid >> 3, nt = bid & 7;
  const int n0 = nt * 64;
  const int tid = threadIdx.x;
  const unsigned short* src = V + ((size_t)bh * N_ + n0) * DH_;
  {
    const int r = tid >> 2, c = (tid & 3) * 16;
    us8 a = *(const us8*)(src + (size_t)r * DH_ + c);
    us8 b8 = *(const us8*)(src + (size_t)r * DH_ + c + 8);
#pragma unroll
    for (int i = 0; i < 8; i++) { t[r][c + i] = a[i]; t[r][c + 8 + i] = b8[i]; }
  }
  __syncthreads();
  {
    const int d = tid >> 2, nc = (tid & 3) * 16;
    us8 o1, o2;
#pragma unroll
    for (int i = 0; i < 8; i++) { o1[i] = t[nc + i][d]; o2[i] = t[nc + 8 + i][d]; }
    unsigned short* dst = Vt + ((size_t)bh * DH_ + d) * N_ + n0 + nc;
    *(us8*)dst = o1;
    *(us8*)(dst + 8) = o2;
  }
}

// ---------------- Fused flash attention ----------------
__global__ __launch_bounds__(256, 3) void attn_kernel(
    const unsigned short* __restrict__ Qs, const unsigned short* __restrict__ Ks,
    const unsigned short* __restrict__ Vt, const unsigned int* __restrict__ packed,
    unsigned short* __restrict__ attn_out) {
  __shared__ unsigned short Kt[64 * 64];    // [ki][d], chunk-XOR-swizzled
  __shared__ unsigned short Vtt[64 * 64];   // [d][ki], chunk-XOR-swizzled

  const int bid = xcd_swz(blockIdx.x, gridDim.x);
  const int qt = bid & 7, h = (bid >> 3) & 7, b = bid >> 6;
  const int q0 = qt * 64;
  const int tid = threadIdx.x, wave = tid >> 6, lane = tid & 63;
  const int q = lane & 15, hi = lane >> 4;

  const int q_g = q0 + wave * 16 + q;  // this lane's q row
  const size_t bh = (size_t)b * H_ + h;
  const unsigned short* Qb = Qs + (bh * N_ + q_g) * DH_;
  bf16x8 qf[2];
  qf[0] = *(const bf16x8*)(Qb + hi * 8);
  qf[1] = *(const bf16x8*)(Qb + 32 + hi * 8);

  const unsigned short* Kb = Ks + bh * N_ * DH_;
  const unsigned short* Vb = Vt + bh * DH_ * N_;
  const unsigned int* Pbase = packed + (size_t)b * N_ * N_ + q_g;

  f32x4 o[4];
#pragma unroll
  for (int i = 0; i < 4; i++) o[i] = (f32x4){0.f, 0.f, 0.f, 0.f};
  float dsum = 0.f;

  const int str = tid >> 2;
  const int stc = tid & 3;

  us8 pk0, pk1, pv0, pv1;
  unsigned int ppw[16];

  auto load_tile = [&](int kt) {
    const unsigned short* Kp = Kb + (size_t)(kt + str) * DH_ + stc * 16;
    const unsigned short* Vp = Vb + (size_t)str * N_ + kt + stc * 16;
    pk0 = *(const us8*)Kp;
    pk1 = *(const us8*)(Kp + 8);
    pv0 = *(const us8*)Vp;
    pv1 = *(const us8*)(Vp + 8);
    const unsigned int* Pp = Pbase + (size_t)(kt + hi * 4) * N_;
#pragma unroll
    for (int c = 0; c < 4; c++)
#pragma unroll
      for (int j = 0; j < 4; j++)
        ppw[c * 4 + j] = Pp[(size_t)(c * 16 + j) * N_];
  };

  load_tile(0);

  for (int kt = 0; kt < N_; kt += 64) {
    __syncthreads();  // all waves done reading previous tile's LDS
    {
      const int c0 = (stc * 2) ^ (str & 7);
      const int c1 = (stc * 2 + 1) ^ (str & 7);
      *(us8*)&Kt[str * 64 + c0 * 8] = pk0;
      *(us8*)&Kt[str * 64 + c1 * 8] = pk1;
      *(us8*)&Vtt[str * 64 + c0 * 8] = pv0;
      *(us8*)&Vtt[str * 64 + c1 * 8] = pv1;
    }
    unsigned int cpw[16];
#pragma unroll
    for (int i = 0; i < 16; i++) cpw[i] = ppw[i];
    __syncthreads();
    if (kt + 64 < N_) load_tile(kt + 64);

    // --- S^T = K * Q^T (Q pre-scaled by 1/8): C[ki][q], col=q, row=hi*4+r ---
    f32x4 s4[4];
#pragma unroll
    for (int c = 0; c < 4; c++) {
      f32x4 a = (f32x4){0.f, 0.f, 0.f, 0.f};
#pragma unroll
      for (int kd = 0; kd < 2; kd++) {
        const int krow = c * 16 + q;
        const int chunk = (kd * 4 + hi) ^ (q & 7);
        bf16x8 kf = *(const bf16x8*)&Kt[krow * 64 + chunk * 8];
        a = __builtin_amdgcn_mfma_f32_16x16x32_bf16(kf, qf[kd], a, 0, 0, 0);
      }
      s4[c] = a;
    }

    // --- softmax: pj = exp(s)*E (denominator), pm = exp(s)*Em (numerator) ---
    unsigned int pkk[4][2];
#pragma unroll
    for (int c = 0; c < 4; c++) {
      float pm[4];
#pragma unroll
      for (int r = 0; r < 4; r++) {
        const float es = __expf(s4[c][r]);
        const unsigned int w = cpw[c * 4 + r];
        dsum += es * b2f((unsigned short)(w & 0xffffu));
        pm[r] = es * b2f((unsigned short)(w >> 16));
      }
      pkk[c][0] = (unsigned int)f2b(pm[0]) | ((unsigned int)f2b(pm[1]) << 16);
      pkk[c][1] = (unsigned int)f2b(pm[2]) | ((unsigned int)f2b(pm[3]) << 16);
    }

    // --- O^T += V^T * P^T : A=Vt rows (lane-local), B=P (registers) ---
#pragma unroll
    for (int dc = 0; dc < 4; dc++) {
      const int vrow = dc * 16 + q;
#pragma unroll
      for (int t = 0; t < 2; t++) {
        u32x4 pb = {pkk[t][0], pkk[t][1], pkk[t + 2][0], pkk[t + 2][1]};
        bf16x8 pf = __builtin_bit_cast(bf16x8, pb);
        const int ch1 = (2 * t + (hi >> 1)) ^ (vrow & 7);
        const int ch2 = (2 * t + 4 + (hi >> 1)) ^ (vrow & 7);
        us4 v1 = *(const us4*)&Vtt[vrow * 64 + ch1 * 8 + (hi & 1) * 4];
        us4 v2 = *(const us4*)&Vtt[vrow * 64 + ch2 * 8 + (hi & 1) * 4];
        us8 vv;
#pragma unroll
        for (int i = 0; i < 4; i++) { vv[i] = v1[i]; vv[4 + i] = v2[i]; }
        bf16x8 vf = __builtin_bit_cast(bf16x8, vv);
        o[dc] = __builtin_amdgcn_mfma_f32_16x16x32_bf16(vf, pf, o[dc], 0, 0, 0);
      }
    }
  }

  // denominator: sum across the 4 hi-groups sharing this q
  dsum += __shfl_xor(dsum, 16);
  dsum += __shfl_xor(dsum, 32);
  const float inv = 1.f / dsum;

  const size_t obase = ((size_t)b * N_ + q_g) * DM_ + h * DH_ + hi * 4;
#pragma unroll
  for (int dc = 0; dc < 4; dc++) {
    us4 ov;
#pragma unroll
    for (int r = 0; r < 4; r++) {
      float val = o[dc][r] * inv;
      val = val >= 0.f ? val : 0.01f * val;  // leaky_relu fused
      ov[r] = f2b(val);
    }
    *(us4*)&attn_out[obase + dc * 16] = ov;
  }
}

extern "C" void kernel_launch(void* const* d_in, const int* in_sizes, int n_in,
                              void* d_out, int out_size, void* d_ws, size_t ws_size,
                              hipStream_t stream) {
  const float* Z     = (const float*)d_in[0];
  const float* D     = (const float*)d_in[1];
  const float* nm    = (const float*)d_in[2];
  const float* mask  = (const float*)d_in[3];
  const float* gamma = (const float*)d_in[4];
  const float* qkv_w = (const float*)d_in[5];
  const float* qkv_b = (const float*)d_in[6];
  const float* o_w   = (const float*)d_in[7];
  const float* ln1_w = (const float*)d_in[8];
  const float* ln1_b = (const float*)d_in[9];
  const float* ln2_w = (const float*)d_in[10];
  const float* ln2_b = (const float*)d_in[11];
  const float* p1_w  = (const float*)d_in[12];
  const float* p1_b  = (const float*)d_in[13];
  const float* p2_w  = (const float*)d_in[14];
  const float* p2_b  = (const float*)d_in[15];
  const int* ra = (const int*)d_in[16];
  const int* rb = (const int*)d_in[17];
  float* out = (float*)d_out;

  const size_t SZ = (size_t)16384 * 512;  // elements per (B*N, DM) buffer
  unsigned short* buf0  = (unsigned short*)d_ws;  // Zn -> attn_act -> Zn2 (bf16)
  unsigned short* bufQ  = buf0 + SZ;
  unsigned short* bufK  = bufQ + SZ;
  unsigned short* bufV  = bufK + SZ;
  unsigned short* bufVt = bufV + SZ;
  float* bufZ = (float*)(bufVt + SZ);             // residual stream (f32, SZ floats)
  unsigned short* bufH = bufQ;                    // FFN hidden reuses Q/K/V/Vt span
  unsigned int* packed = (unsigned int*)bufZ;     // packed E/Em reuses bufZ span
  unsigned short* wQKV = (unsigned short*)(bufZ + SZ);
  unsigned short* wO   = wQKV + (size_t)3 * DM_ * DM_;
  unsigned short* wP1  = wO + (size_t)DM_ * DM_;
  unsigned short* wP2  = wP1 + (size_t)DI_ * DM_;

  // 0. fused prologue: prep_sm (2048) + conv_w (1536) + LN1 (4096)
  fused_pre<<<7680, 256, 0, stream>>>(D, nm, mask, gamma, ra, rb, packed,
                                      qkv_w, o_w, p1_w, p2_w, wQKV, wO, wP1, wP2,
                                      Z, ln1_w, ln1_b, buf0);

  // 2. QKV projection (TM=128, TN=64, grid 3072)
  GemmP p1{};
  p1.A = buf0; p1.Bw = wQKV; p1.bias = qkv_b;
  p1.outb = bufV; p1.out_q = bufQ; p1.out_k = bufK;
  p1.K = 512; p1.tiles_n = 24; p1.ldo = 0;
  gemm_bt<0, 64, 128><<<128 * 24, 256, 0, stream>>>(p1);

  // 3. V transpose
  transp_v<<<2048, 256, 0, stream>>>(bufV, bufVt);

  // 4. Fused attention (incl. leaky_relu)
  attn_kernel<<<B_ * H_ * 8, 256, 0, stream>>>(bufQ, bufK, bufVt, packed, buf0);

  // 5. Output projection + residual (TM=128, TN=64, grid 1024)
  GemmP p3{};
  p3.A = buf0; p3.Bw = wO; p3.residf = Z; p3.outf = bufZ;
  p3.K = 512; p3.tiles_n = 8; p3.ldo = 512;
  gemm_bt<1, 64, 128><<<128 * 8, 256, 0, stream>>>(p3);

  // 6. LN2 (f32 -> bf16)
  ln_kernel<<<4096, 256, 0, stream>>>(bufZ, ln2_w, ln2_b, buf0);

  // 7. FFN up + relu (TM=128, TN=128, grid 2048)
  GemmP p5{};
  p5.A = buf0; p5.Bw = wP1; p5.bias = p1_b; p5.outb = bufH;
  p5.K = 512; p5.tiles_n = 16; p5.ldo = 2048;
  gemm_bt<2, 128, 128><<<128 * 16, 256, 0, stream>>>(p5);

  // 8. FFN down + bias + residual -> out (TM=64, TN=64, grid 2048 -> 8 blocks/CU)
  GemmP p6{};
  p6.A = bufH; p6.Bw = wP2; p6.bias = p2_b; p6.residf = bufZ; p6.outf = out;
  p6.K = 2048; p6.tiles_n = 8; p6.ldo = 512;
  gemm_bt<3, 64, 64><<<256 * 8, 256, 0, stream>>>(p6);
}

// Round 20
// 282.179 us; speedup vs baseline: 1.0437x; 1.0437x over previous
//
#include <hip/hip_runtime.h>
#include <hip/hip_bf16.h>

// Problem constants
#define B_  32
#define N_  512
#define DM_ 512
#define H_  8
#define DH_ 64
#define DI_ 2048

typedef __attribute__((ext_vector_type(8))) __bf16 bf16x8;
typedef __attribute__((ext_vector_type(4))) float f32x4;
typedef __attribute__((ext_vector_type(8))) unsigned short us8;
typedef __attribute__((ext_vector_type(4))) unsigned short us4;
typedef __attribute__((ext_vector_type(4))) unsigned int u32x4;

typedef __attribute__((address_space(1))) const void g_cvoid;
typedef __attribute__((address_space(3))) void l_void;

__device__ __forceinline__ float b2f(unsigned short u) {
  union { unsigned int i; float f; } x; x.i = ((unsigned int)u) << 16; return x.f;
}
__device__ __forceinline__ unsigned short f2b(float f) {
  union { float f; unsigned int i; } x; x.f = f;
  unsigned int r = x.i + 0x7FFFu + ((x.i >> 16) & 1u);
  return (unsigned short)(r >> 16);
}
__device__ __forceinline__ void gld_lds16(const unsigned short* g, unsigned short* l) {
  __builtin_amdgcn_global_load_lds((g_cvoid*)g, (l_void*)l, 16, 0, 0);
}
// bijective XCD swizzle for grids with nwg % 8 == 0
__device__ __forceinline__ int xcd_swz(int bid, int nwg) {
  return (bid & 7) * (nwg >> 3) + (bid >> 3);
}

// ---------------- fused prologue: prep_sm (2048 blocks) + conv_w (1536) + LN1 (4096) ----------------
__global__ __launch_bounds__(256) void fused_pre(
    const float* __restrict__ Dg, const float* __restrict__ nmg,
    const float* __restrict__ mkg, const float* __restrict__ gammaf,
    const int* __restrict__ ra, const int* __restrict__ rb,
    unsigned int* __restrict__ packed,
    const float* __restrict__ wa, const float* __restrict__ wb,
    const float* __restrict__ wc, const float* __restrict__ wd,
    unsigned short* __restrict__ oa, unsigned short* __restrict__ ob,
    unsigned short* __restrict__ oc, unsigned short* __restrict__ od,
    const float* __restrict__ x, const float* __restrict__ lw,
    const float* __restrict__ lb, unsigned short* __restrict__ y) {
  __shared__ unsigned int t[64][65];
  const int blk = blockIdx.x;
  const int tid = threadIdx.x;
  if (blk < 2048) {
    // ---- prep_sm: E=exp(nm-gamma*D), Em=E*mask, packed [b][ki][q] ----
    const int kt = blk & 7, qt = (blk >> 3) & 7, b = blk >> 6;
    const int ra_e = *ra, rb_e = *rb;
    const int r = tid >> 2;
    const int c = (tid & 3) * 16;
    const int q_g = qt * 64 + r;
    const int rq = (q_g >= ra_e) + (q_g >= rb_e);
    const float g0 = gammaf[rq * 4], g1 = gammaf[rq * 4 + 1], g2 = gammaf[rq * 4 + 2];
    const size_t base = ((size_t)b * N_ + q_g) * N_ + kt * 64 + c;
#pragma unroll
    for (int i = 0; i < 4; i++) {
      f32x4 dv = *(const f32x4*)(Dg + base + i * 4);
      f32x4 nv = *(const f32x4*)(nmg + base + i * 4);
      f32x4 mv = *(const f32x4*)(mkg + base + i * 4);
#pragma unroll
      for (int j = 0; j < 4; j++) {
        const int gk = kt * 64 + c + i * 4 + j;
        const float g = gk >= rb_e ? g2 : (gk >= ra_e ? g1 : g0);
        const float E = __expf(nv[j] - g * dv[j]);
        const float Em = E * mv[j];
        t[r][c + i * 4 + j] = (unsigned int)f2b(E) | ((unsigned int)f2b(Em) << 16);
      }
    }
    __syncthreads();
    const int rr = tid >> 2;
    const int cc = (tid & 3) * 16;
    unsigned int* dst = packed + ((size_t)b * N_ + kt * 64 + rr) * N_ + qt * 64 + cc;
#pragma unroll
    for (int i = 0; i < 4; i++) {
      u32x4 v;
#pragma unroll
      for (int j = 0; j < 4; j++) v[j] = t[cc + i * 4 + j][rr];
      *(u32x4*)(dst + i * 4) = v;
    }
  } else if (blk < 3584) {
    // ---- conv_w: f32 -> bf16 weight conversion ----
    const int bid = blk - 2048;
    const float* src; unsigned short* dst; int idx;
    if (bid < 384)       { src = wa; dst = oa; idx = bid; }
    else if (bid < 512)  { src = wb; dst = ob; idx = bid - 384; }
    else if (bid < 1024) { src = wc; dst = oc; idx = bid - 512; }
    else                 { src = wd; dst = od; idx = bid - 1024; }
    const int off = idx * 2048 + tid * 8;
    f32x4 x0 = *(const f32x4*)(src + off);
    f32x4 x1 = *(const f32x4*)(src + off + 4);
    us8 o;
#pragma unroll
    for (int i = 0; i < 4; i++) { o[i] = f2b(x0[i]); o[4 + i] = f2b(x1[i]); }
    *(us8*)(dst + off) = o;
  } else {
    // ---- LN1: f32 -> bf16, one wave per row ----
    const int row  = (blk - 3584) * 4 + (tid >> 6);
    const int lane = tid & 63;
    const float* xr = x + (size_t)row * DM_ + lane * 8;
    f32x4 x0 = *(const f32x4*)xr;
    f32x4 x1 = *(const f32x4*)(xr + 4);
    float v[8]; float s = 0.f;
#pragma unroll
    for (int i = 0; i < 4; i++) { v[i] = x0[i]; v[4 + i] = x1[i]; }
#pragma unroll
    for (int i = 0; i < 8; i++) s += v[i];
#pragma unroll
    for (int o = 1; o < 64; o <<= 1) s += __shfl_xor(s, o);
    const float mu = s * (1.f / DM_);
    float q = 0.f;
#pragma unroll
    for (int i = 0; i < 8; i++) { float d = v[i] - mu; q += d * d; }
#pragma unroll
    for (int o = 1; o < 64; o <<= 1) q += __shfl_xor(q, o);
    const float rstd = rsqrtf(q * (1.f / DM_) + 1e-5f);
    f32x4 w0 = *(const f32x4*)(lw + lane * 8);
    f32x4 w1 = *(const f32x4*)(lw + lane * 8 + 4);
    f32x4 b0 = *(const f32x4*)(lb + lane * 8);
    f32x4 b1 = *(const f32x4*)(lb + lane * 8 + 4);
    us8 out;
#pragma unroll
    for (int i = 0; i < 4; i++) {
      out[i]     = f2b((v[i] - mu) * rstd * w0[i] + b0[i]);
      out[4 + i] = f2b((v[4 + i] - mu) * rstd * w1[i] + b1[i]);
    }
    *(us8*)(y + (size_t)row * DM_ + lane * 8) = out;
  }
}

// ---------------- LayerNorm (f32 in, bf16 out): one wave per row of 512 ----------------
__global__ __launch_bounds__(256) void ln_kernel(const float* __restrict__ x,
                                                 const float* __restrict__ w,
                                                 const float* __restrict__ b,
                                                 unsigned short* __restrict__ y) {
  const int row  = blockIdx.x * 4 + (threadIdx.x >> 6);
  const int lane = threadIdx.x & 63;
  const float* xr = x + (size_t)row * DM_ + lane * 8;
  f32x4 x0 = *(const f32x4*)xr;
  f32x4 x1 = *(const f32x4*)(xr + 4);
  float v[8]; float s = 0.f;
#pragma unroll
  for (int i = 0; i < 4; i++) { v[i] = x0[i]; v[4 + i] = x1[i]; }
#pragma unroll
  for (int i = 0; i < 8; i++) s += v[i];
#pragma unroll
  for (int o = 1; o < 64; o <<= 1) s += __shfl_xor(s, o);
  const float mu = s * (1.f / DM_);
  float q = 0.f;
#pragma unroll
  for (int i = 0; i < 8; i++) { float d = v[i] - mu; q += d * d; }
#pragma unroll
  for (int o = 1; o < 64; o <<= 1) q += __shfl_xor(q, o);
  const float rstd = rsqrtf(q * (1.f / DM_) + 1e-5f);
  f32x4 w0 = *(const f32x4*)(w + lane * 8);
  f32x4 w1 = *(const f32x4*)(w + lane * 8 + 4);
  f32x4 b0 = *(const f32x4*)(b + lane * 8);
  f32x4 b1 = *(const f32x4*)(b + lane * 8 + 4);
  us8 out;
#pragma unroll
  for (int i = 0; i < 4; i++) {
    out[i]     = f2b((v[i] - mu) * rstd * w0[i] + b0[i]);
    out[4 + i] = f2b((v[4 + i] - mu) * rstd * w1[i] + b1[i]);
  }
  *(us8*)(y + (size_t)row * DM_ + lane * 8) = out;
}

// ---------------- GEMM: C = A(MxK,bf16) * B(NxK,bf16)^T, 128xTN tile, BK=32 ----------------
// 2-phase double-buffered LDS pipeline; R9-exact epilogue; 4-chunk XOR source
// swizzle (bank conflicts = 0, R14-verified). EPI==0 writes V directly in
// transposed [b][h][d][n] layout (transp_v kernel eliminated).
struct GemmP {
  const unsigned short* A;
  const unsigned short* Bw;
  const float* bias;
  const float* residf;
  unsigned short* outb;
  float* outf;
  unsigned short* out_q;
  unsigned short* out_k;
  int K;
  int tiles_n;
  int ldo;
};

// EPI: 0=QKV scatter(bf16, V transposed), 1=+resid->f32, 2=relu(+bias)->bf16, 3=+bias+resid->f32
template <int EPI, int TN>
__global__ __launch_bounds__(256) void gemm_bt(GemmP p) {
  constexpr int NFR = TN / 32;  // n-frags per wave
  __shared__ unsigned short As[2][128 * 32];
  __shared__ unsigned short Bs[2][TN * 32];
  const int tid = threadIdx.x;
  const int wave = tid >> 6, lane = tid & 63;
  const int wm = wave >> 1, wn = wave & 1;
  const int bid = xcd_swz(blockIdx.x, gridDim.x);
  const int tn = bid % p.tiles_n, tm = bid / p.tiles_n;
  const int K = p.K;
  const unsigned short* Ab = p.A + (size_t)tm * 128 * K;
  const unsigned short* Bb = p.Bw + (size_t)tn * TN * K;
  f32x4 acc[4][NFR];
#pragma unroll
  for (int i = 0; i < 4; i++)
#pragma unroll
    for (int j = 0; j < NFR; j++) acc[i][j] = (f32x4){0.f, 0.f, 0.f, 0.f};

  const int l15 = lane & 15;
  const int srow = lane >> 2;
  const int scol = (((lane & 3) ^ ((srow >> 1) & 3))) * 8;  // source-swizzled chunk
  auto stage = [&](int buf, int kt) {
#pragma unroll
    for (int i = 0; i < 2; i++) {
      const int r = wave * 32 + i * 16;
      gld_lds16(Ab + (size_t)(r + srow) * K + kt + scol, &As[buf][r * 32]);
    }
    if (TN == 128) {
#pragma unroll
      for (int i = 0; i < 2; i++) {
        const int r = wave * 32 + i * 16;
        gld_lds16(Bb + (size_t)(r + srow) * K + kt + scol, &Bs[buf][r * 32]);
      }
    } else {
      const int r = wave * 16;
      gld_lds16(Bb + (size_t)(r + srow) * K + kt + scol, &Bs[buf][r * 32]);
    }
  };

  stage(0, 0);
  __syncthreads();  // buf0 ready
  const int nIter = K >> 5;
  const int rchunk = (((lane >> 4) ^ ((l15 >> 1) & 3))) * 8;  // swizzled read slot
  for (int it = 0; it < nIter; it++) {
    const int buf = it & 1;
    if (it + 1 < nIter) stage(buf ^ 1, (it + 1) * 32);  // overlap with compute
    bf16x8 af[4], bfr[NFR];
#pragma unroll
    for (int m = 0; m < 4; m++)
      af[m] = *(const bf16x8*)&As[buf][(wm * 64 + m * 16 + l15) * 32 + rchunk];
#pragma unroll
    for (int n = 0; n < NFR; n++)
      bfr[n] = *(const bf16x8*)&Bs[buf][(wn * (TN / 2) + n * 16 + l15) * 32 + rchunk];
#pragma unroll
    for (int m = 0; m < 4; m++)
#pragma unroll
      for (int n = 0; n < NFR; n++)
        acc[m][n] = __builtin_amdgcn_mfma_f32_16x16x32_bf16(af[m], bfr[n], acc[m][n], 0, 0, 0);
    __syncthreads();  // next buf staged + all waves done reading this buf
  }

  const int r0 = tm * 128 + wm * 64;
  const int c0 = tn * TN + wn * (TN / 2);
#pragma unroll
  for (int m = 0; m < 4; m++) {
#pragma unroll
    for (int n = 0; n < NFR; n++) {
#pragma unroll
      for (int rr = 0; rr < 4; rr++) {
        const int row = r0 + m * 16 + (lane >> 4) * 4 + rr;
        const int col = c0 + n * 16 + (lane & 15);
        float v = acc[m][n][rr];
        if (EPI == 0) {
          v += p.bias[col];
          const int h = col / 192, j = col % 192;
          const int bb = row >> 9, nn = row & 511;
          const size_t bh = (size_t)bb * H_ + h;
          if (j < 64)       p.outb [(bh * DH_ + j) * N_ + nn]      = f2b(v);           // V (transposed)
          else if (j < 128) p.out_q[(bh * N_ + nn) * DH_ + j - 64] = f2b(v * 0.125f);  // Q (scale folded)
          else              p.out_k[(bh * N_ + nn) * DH_ + j - 128] = f2b(v);          // K
        } else if (EPI == 1) {
          p.outf[(size_t)row * p.ldo + col] = v + p.residf[(size_t)row * p.ldo + col];
        } else if (EPI == 2) {
          v += p.bias[col];
          v = v > 0.f ? v : 0.f;
          p.outb[(size_t)row * p.ldo + col] = f2b(v);
        } else {
          p.outf[(size_t)row * p.ldo + col] =
              v + p.bias[col] + p.residf[(size_t)row * p.ldo + col];
        }
      }
    }
  }
}

// ---------------- Fused flash attention ----------------
__global__ __launch_bounds__(256, 3) void attn_kernel(
    const unsigned short* __restrict__ Qs, const unsigned short* __restrict__ Ks,
    const unsigned short* __restrict__ Vt, const unsigned int* __restrict__ packed,
    unsigned short* __restrict__ attn_out) {
  __shared__ unsigned short Kt[64 * 64];    // [ki][d], chunk-XOR-swizzled
  __shared__ unsigned short Vtt[64 * 64];   // [d][ki], chunk-XOR-swizzled

  const int bid = xcd_swz(blockIdx.x, gridDim.x);
  const int qt = bid & 7, h = (bid >> 3) & 7, b = bid >> 6;
  const int q0 = qt * 64;
  const int tid = threadIdx.x, wave = tid >> 6, lane = tid & 63;
  const int q = lane & 15, hi = lane >> 4;

  const int q_g = q0 + wave * 16 + q;  // this lane's q row
  const size_t bh = (size_t)b * H_ + h;
  const unsigned short* Qb = Qs + (bh * N_ + q_g) * DH_;
  bf16x8 qf[2];
  qf[0] = *(const bf16x8*)(Qb + hi * 8);
  qf[1] = *(const bf16x8*)(Qb + 32 + hi * 8);

  const unsigned short* Kb = Ks + bh * N_ * DH_;
  const unsigned short* Vb = Vt + bh * DH_ * N_;
  const unsigned int* Pbase = packed + (size_t)b * N_ * N_ + q_g;

  f32x4 o[4];
#pragma unroll
  for (int i = 0; i < 4; i++) o[i] = (f32x4){0.f, 0.f, 0.f, 0.f};
  float dsum = 0.f;

  const int str = tid >> 2;
  const int stc = tid & 3;

  us8 pk0, pk1, pv0, pv1;
  unsigned int ppw[16];

  auto load_tile = [&](int kt) {
    const unsigned short* Kp = Kb + (size_t)(kt + str) * DH_ + stc * 16;
    const unsigned short* Vp = Vb + (size_t)str * N_ + kt + stc * 16;
    pk0 = *(const us8*)Kp;
    pk1 = *(const us8*)(Kp + 8);
    pv0 = *(const us8*)Vp;
    pv1 = *(const us8*)(Vp + 8);
    const unsigned int* Pp = Pbase + (size_t)(kt + hi * 4) * N_;
#pragma unroll
    for (int c = 0; c < 4; c++)
#pragma unroll
      for (int j = 0; j < 4; j++)
        ppw[c * 4 + j] = Pp[(size_t)(c * 16 + j) * N_];
  };

  load_tile(0);

  for (int kt = 0; kt < N_; kt += 64) {
    __syncthreads();  // all waves done reading previous tile's LDS
    {
      const int c0 = (stc * 2) ^ (str & 7);
      const int c1 = (stc * 2 + 1) ^ (str & 7);
      *(us8*)&Kt[str * 64 + c0 * 8] = pk0;
      *(us8*)&Kt[str * 64 + c1 * 8] = pk1;
      *(us8*)&Vtt[str * 64 + c0 * 8] = pv0;
      *(us8*)&Vtt[str * 64 + c1 * 8] = pv1;
    }
    unsigned int cpw[16];
#pragma unroll
    for (int i = 0; i < 16; i++) cpw[i] = ppw[i];
    __syncthreads();
    if (kt + 64 < N_) load_tile(kt + 64);

    // --- S^T = K * Q^T (Q pre-scaled by 1/8): C[ki][q], col=q, row=hi*4+r ---
    f32x4 s4[4];
#pragma unroll
    for (int c = 0; c < 4; c++) {
      f32x4 a = (f32x4){0.f, 0.f, 0.f, 0.f};
#pragma unroll
      for (int kd = 0; kd < 2; kd++) {
        const int krow = c * 16 + q;
        const int chunk = (kd * 4 + hi) ^ (q & 7);
        bf16x8 kf = *(const bf16x8*)&Kt[krow * 64 + chunk * 8];
        a = __builtin_amdgcn_mfma_f32_16x16x32_bf16(kf, qf[kd], a, 0, 0, 0);
      }
      s4[c] = a;
    }

    // --- softmax: pj = exp(s)*E (denominator), pm = exp(s)*Em (numerator) ---
    unsigned int pkk[4][2];
#pragma unroll
    for (int c = 0; c < 4; c++) {
      float pm[4];
#pragma unroll
      for (int r = 0; r < 4; r++) {
        const float es = __expf(s4[c][r]);
        const unsigned int w = cpw[c * 4 + r];
        dsum += es * b2f((unsigned short)(w & 0xffffu));
        pm[r] = es * b2f((unsigned short)(w >> 16));
      }
      pkk[c][0] = (unsigned int)f2b(pm[0]) | ((unsigned int)f2b(pm[1]) << 16);
      pkk[c][1] = (unsigned int)f2b(pm[2]) | ((unsigned int)f2b(pm[3]) << 16);
    }

    // --- O^T += V^T * P^T : A=Vt rows (lane-local), B=P (registers) ---
#pragma unroll
    for (int dc = 0; dc < 4; dc++) {
      const int vrow = dc * 16 + q;
#pragma unroll
      for (int t = 0; t < 2; t++) {
        u32x4 pb = {pkk[t][0], pkk[t][1], pkk[t + 2][0], pkk[t + 2][1]};
        bf16x8 pf = __builtin_bit_cast(bf16x8, pb);
        const int ch1 = (2 * t + (hi >> 1)) ^ (vrow & 7);
        const int ch2 = (2 * t + 4 + (hi >> 1)) ^ (vrow & 7);
        us4 v1 = *(const us4*)&Vtt[vrow * 64 + ch1 * 8 + (hi & 1) * 4];
        us4 v2 = *(const us4*)&Vtt[vrow * 64 + ch2 * 8 + (hi & 1) * 4];
        us8 vv;
#pragma unroll
        for (int i = 0; i < 4; i++) { vv[i] = v1[i]; vv[4 + i] = v2[i]; }
        bf16x8 vf = __builtin_bit_cast(bf16x8, vv);
        o[dc] = __builtin_amdgcn_mfma_f32_16x16x32_bf16(vf, pf, o[dc], 0, 0, 0);
      }
    }
  }

  // denominator: sum across the 4 hi-groups sharing this q
  dsum += __shfl_xor(dsum, 16);
  dsum += __shfl_xor(dsum, 32);
  const float inv = 1.f / dsum;

  const size_t obase = ((size_t)b * N_ + q_g) * DM_ + h * DH_ + hi * 4;
#pragma unroll
  for (int dc = 0; dc < 4; dc++) {
    us4 ov;
#pragma unroll
    for (int r = 0; r < 4; r++) {
      float val = o[dc][r] * inv;
      val = val >= 0.f ? val : 0.01f * val;  // leaky_relu fused
      ov[r] = f2b(val);
    }
    *(us4*)&attn_out[obase + dc * 16] = ov;
  }
}

extern "C" void kernel_launch(void* const* d_in, const int* in_sizes, int n_in,
                              void* d_out, int out_size, void* d_ws, size_t ws_size,
                              hipStream_t stream) {
  const float* Z     = (const float*)d_in[0];
  const float* D     = (const float*)d_in[1];
  const float* nm    = (const float*)d_in[2];
  const float* mask  = (const float*)d_in[3];
  const float* gamma = (const float*)d_in[4];
  const float* qkv_w = (const float*)d_in[5];
  const float* qkv_b = (const float*)d_in[6];
  const float* o_w   = (const float*)d_in[7];
  const float* ln1_w = (const float*)d_in[8];
  const float* ln1_b = (const float*)d_in[9];
  const float* ln2_w = (const float*)d_in[10];
  const float* ln2_b = (const float*)d_in[11];
  const float* p1_w  = (const float*)d_in[12];
  const float* p1_b  = (const float*)d_in[13];
  const float* p2_w  = (const float*)d_in[14];
  const float* p2_b  = (const float*)d_in[15];
  const int* ra = (const int*)d_in[16];
  const int* rb = (const int*)d_in[17];
  float* out = (float*)d_out;

  const size_t SZ = (size_t)16384 * 512;  // elements per (B*N, DM) buffer
  unsigned short* buf0  = (unsigned short*)d_ws;  // Zn -> attn_act -> Zn2 (bf16)
  unsigned short* bufQ  = buf0 + SZ;
  unsigned short* bufK  = bufQ + SZ;
  unsigned short* bufVt = bufK + SZ;              // V written directly transposed
  float* bufZ = (float*)(bufVt + 2 * SZ);         // residual stream (f32, SZ floats)
  unsigned short* bufH = bufQ;                    // FFN hidden reuses Q/K/Vt span
  unsigned int* packed = (unsigned int*)bufZ;     // packed E/Em reuses bufZ span
  unsigned short* wQKV = (unsigned short*)(bufZ + SZ);
  unsigned short* wO   = wQKV + (size_t)3 * DM_ * DM_;
  unsigned short* wP1  = wO + (size_t)DM_ * DM_;
  unsigned short* wP2  = wP1 + (size_t)DI_ * DM_;

  // 0. fused prologue: prep_sm (2048) + conv_w (1536) + LN1 (4096)
  fused_pre<<<7680, 256, 0, stream>>>(D, nm, mask, gamma, ra, rb, packed,
                                      qkv_w, o_w, p1_w, p2_w, wQKV, wO, wP1, wP2,
                                      Z, ln1_w, ln1_b, buf0);

  // 2. QKV projection (TN=64, grid 3072; V written transposed -> no transp_v)
  GemmP p1{};
  p1.A = buf0; p1.Bw = wQKV; p1.bias = qkv_b;
  p1.outb = bufVt; p1.out_q = bufQ; p1.out_k = bufK;
  p1.K = 512; p1.tiles_n = 24; p1.ldo = 0;
  gemm_bt<0, 64><<<128 * 24, 256, 0, stream>>>(p1);

  // 4. Fused attention (incl. leaky_relu)
  attn_kernel<<<B_ * H_ * 8, 256, 0, stream>>>(bufQ, bufK, bufVt, packed, buf0);

  // 5. Output projection + residual (TN=64, grid 1024)
  GemmP p3{};
  p3.A = buf0; p3.Bw = wO; p3.residf = Z; p3.outf = bufZ;
  p3.K = 512; p3.tiles_n = 8; p3.ldo = 512;
  gemm_bt<1, 64><<<128 * 8, 256, 0, stream>>>(p3);

  // 6. LN2 (f32 -> bf16)
  ln_kernel<<<4096, 256, 0, stream>>>(bufZ, ln2_w, ln2_b, buf0);

  // 7. FFN up + relu (TN=128, grid 2048)
  GemmP p5{};
  p5.A = buf0; p5.Bw = wP1; p5.bias = p1_b; p5.outb = bufH;
  p5.K = 512; p5.tiles_n = 16; p5.ldo = 2048;
  gemm_bt<2, 128><<<128 * 16, 256, 0, stream>>>(p5);

  // 8. FFN down + bias + residual -> out (TN=64, grid 1024)
  GemmP p6{};
  p6.A = bufH; p6.Bw = wP2; p6.bias = p2_b; p6.residf = bufZ; p6.outf = out;
  p6.K = 2048; p6.tiles_n = 8; p6.ldo = 512;
  gemm_bt<3, 64><<<128 * 8, 256, 0, stream>>>(p6);
}

// Round 21
// 275.210 us; speedup vs baseline: 1.0701x; 1.0253x over previous
//
#include <hip/hip_runtime.h>
#include <hip/hip_bf16.h>

// Problem constants
#define B_  32
#define N_  512
#define DM_ 512
#define H_  8
#define DH_ 64
#define DI_ 2048

typedef __attribute__((ext_vector_type(8))) __bf16 bf16x8;
typedef __attribute__((ext_vector_type(4))) float f32x4;
typedef __attribute__((ext_vector_type(8))) unsigned short us8;
typedef __attribute__((ext_vector_type(4))) unsigned short us4;
typedef __attribute__((ext_vector_type(4))) unsigned int u32x4;

typedef __attribute__((address_space(1))) const void g_cvoid;
typedef __attribute__((address_space(3))) void l_void;

__device__ __forceinline__ float b2f(unsigned short u) {
  union { unsigned int i; float f; } x; x.i = ((unsigned int)u) << 16; return x.f;
}
__device__ __forceinline__ unsigned short f2b(float f) {
  union { float f; unsigned int i; } x; x.f = f;
  unsigned int r = x.i + 0x7FFFu + ((x.i >> 16) & 1u);
  return (unsigned short)(r >> 16);
}
__device__ __forceinline__ void gld_lds16(const unsigned short* g, unsigned short* l) {
  __builtin_amdgcn_global_load_lds((g_cvoid*)g, (l_void*)l, 16, 0, 0);
}
// bijective XCD swizzle for grids with nwg % 8 == 0
__device__ __forceinline__ int xcd_swz(int bid, int nwg) {
  return (bid & 7) * (nwg >> 3) + (bid >> 3);
}

// ---------------- fused prologue: prep_sm (2048 blocks) + conv_w (1536) + LN1 (4096) ----------------
__global__ __launch_bounds__(256) void fused_pre(
    const float* __restrict__ Dg, const float* __restrict__ nmg,
    const float* __restrict__ mkg, const float* __restrict__ gammaf,
    const int* __restrict__ ra, const int* __restrict__ rb,
    unsigned int* __restrict__ packed,
    const float* __restrict__ wa, const float* __restrict__ wb,
    const float* __restrict__ wc, const float* __restrict__ wd,
    unsigned short* __restrict__ oa, unsigned short* __restrict__ ob,
    unsigned short* __restrict__ oc, unsigned short* __restrict__ od,
    const float* __restrict__ x, const float* __restrict__ lw,
    const float* __restrict__ lb, unsigned short* __restrict__ y) {
  __shared__ unsigned int t[64][65];
  const int blk = blockIdx.x;
  const int tid = threadIdx.x;
  if (blk < 2048) {
    // ---- prep_sm: E=exp(nm-gamma*D), Em=E*mask, packed [b][ki][q] ----
    const int kt = blk & 7, qt = (blk >> 3) & 7, b = blk >> 6;
    const int ra_e = *ra, rb_e = *rb;
    const int r = tid >> 2;
    const int c = (tid & 3) * 16;
    const int q_g = qt * 64 + r;
    const int rq = (q_g >= ra_e) + (q_g >= rb_e);
    const float g0 = gammaf[rq * 4], g1 = gammaf[rq * 4 + 1], g2 = gammaf[rq * 4 + 2];
    const size_t base = ((size_t)b * N_ + q_g) * N_ + kt * 64 + c;
#pragma unroll
    for (int i = 0; i < 4; i++) {
      f32x4 dv = *(const f32x4*)(Dg + base + i * 4);
      f32x4 nv = *(const f32x4*)(nmg + base + i * 4);
      f32x4 mv = *(const f32x4*)(mkg + base + i * 4);
#pragma unroll
      for (int j = 0; j < 4; j++) {
        const int gk = kt * 64 + c + i * 4 + j;
        const float g = gk >= rb_e ? g2 : (gk >= ra_e ? g1 : g0);
        const float E = __expf(nv[j] - g * dv[j]);
        const float Em = E * mv[j];
        t[r][c + i * 4 + j] = (unsigned int)f2b(E) | ((unsigned int)f2b(Em) << 16);
      }
    }
    __syncthreads();
    const int rr = tid >> 2;
    const int cc = (tid & 3) * 16;
    unsigned int* dst = packed + ((size_t)b * N_ + kt * 64 + rr) * N_ + qt * 64 + cc;
#pragma unroll
    for (int i = 0; i < 4; i++) {
      u32x4 v;
#pragma unroll
      for (int j = 0; j < 4; j++) v[j] = t[cc + i * 4 + j][rr];
      *(u32x4*)(dst + i * 4) = v;
    }
  } else if (blk < 3584) {
    // ---- conv_w: f32 -> bf16 weight conversion ----
    const int bid = blk - 2048;
    const float* src; unsigned short* dst; int idx;
    if (bid < 384)       { src = wa; dst = oa; idx = bid; }
    else if (bid < 512)  { src = wb; dst = ob; idx = bid - 384; }
    else if (bid < 1024) { src = wc; dst = oc; idx = bid - 512; }
    else                 { src = wd; dst = od; idx = bid - 1024; }
    const int off = idx * 2048 + tid * 8;
    f32x4 x0 = *(const f32x4*)(src + off);
    f32x4 x1 = *(const f32x4*)(src + off + 4);
    us8 o;
#pragma unroll
    for (int i = 0; i < 4; i++) { o[i] = f2b(x0[i]); o[4 + i] = f2b(x1[i]); }
    *(us8*)(dst + off) = o;
  } else {
    // ---- LN1: f32 -> bf16, one wave per row ----
    const int row  = (blk - 3584) * 4 + (tid >> 6);
    const int lane = tid & 63;
    const float* xr = x + (size_t)row * DM_ + lane * 8;
    f32x4 x0 = *(const f32x4*)xr;
    f32x4 x1 = *(const f32x4*)(xr + 4);
    float v[8]; float s = 0.f;
#pragma unroll
    for (int i = 0; i < 4; i++) { v[i] = x0[i]; v[4 + i] = x1[i]; }
#pragma unroll
    for (int i = 0; i < 8; i++) s += v[i];
#pragma unroll
    for (int o = 1; o < 64; o <<= 1) s += __shfl_xor(s, o);
    const float mu = s * (1.f / DM_);
    float q = 0.f;
#pragma unroll
    for (int i = 0; i < 8; i++) { float d = v[i] - mu; q += d * d; }
#pragma unroll
    for (int o = 1; o < 64; o <<= 1) q += __shfl_xor(q, o);
    const float rstd = rsqrtf(q * (1.f / DM_) + 1e-5f);
    f32x4 w0 = *(const f32x4*)(lw + lane * 8);
    f32x4 w1 = *(const f32x4*)(lw + lane * 8 + 4);
    f32x4 b0 = *(const f32x4*)(lb + lane * 8);
    f32x4 b1 = *(const f32x4*)(lb + lane * 8 + 4);
    us8 out;
#pragma unroll
    for (int i = 0; i < 4; i++) {
      out[i]     = f2b((v[i] - mu) * rstd * w0[i] + b0[i]);
      out[4 + i] = f2b((v[4 + i] - mu) * rstd * w1[i] + b1[i]);
    }
    *(us8*)(y + (size_t)row * DM_ + lane * 8) = out;
  }
}

// ---------------- LayerNorm (f32 in, bf16 out): one wave per row of 512 ----------------
__global__ __launch_bounds__(256) void ln_kernel(const float* __restrict__ x,
                                                 const float* __restrict__ w,
                                                 const float* __restrict__ b,
                                                 unsigned short* __restrict__ y) {
  const int row  = blockIdx.x * 4 + (threadIdx.x >> 6);
  const int lane = threadIdx.x & 63;
  const float* xr = x + (size_t)row * DM_ + lane * 8;
  f32x4 x0 = *(const f32x4*)xr;
  f32x4 x1 = *(const f32x4*)(xr + 4);
  float v[8]; float s = 0.f;
#pragma unroll
  for (int i = 0; i < 4; i++) { v[i] = x0[i]; v[4 + i] = x1[i]; }
#pragma unroll
  for (int i = 0; i < 8; i++) s += v[i];
#pragma unroll
  for (int o = 1; o < 64; o <<= 1) s += __shfl_xor(s, o);
  const float mu = s * (1.f / DM_);
  float q = 0.f;
#pragma unroll
  for (int i = 0; i < 8; i++) { float d = v[i] - mu; q += d * d; }
#pragma unroll
  for (int o = 1; o < 64; o <<= 1) q += __shfl_xor(q, o);
  const float rstd = rsqrtf(q * (1.f / DM_) + 1e-5f);
  f32x4 w0 = *(const f32x4*)(w + lane * 8);
  f32x4 w1 = *(const f32x4*)(w + lane * 8 + 4);
  f32x4 b0 = *(const f32x4*)(b + lane * 8);
  f32x4 b1 = *(const f32x4*)(b + lane * 8 + 4);
  us8 out;
#pragma unroll
  for (int i = 0; i < 4; i++) {
    out[i]     = f2b((v[i] - mu) * rstd * w0[i] + b0[i]);
    out[4 + i] = f2b((v[4 + i] - mu) * rstd * w1[i] + b1[i]);
  }
  *(us8*)(y + (size_t)row * DM_ + lane * 8) = out;
}

// ---------------- GEMM: C = A(MxK,bf16) * B(NxK,bf16)^T, 128xTN tile, BK=32 ----------------
// 2-phase double-buffered LDS pipeline; R9-exact epilogue; 4-chunk XOR source
// swizzle (bank conflicts = 0, R14-verified).
struct GemmP {
  const unsigned short* A;
  const unsigned short* Bw;
  const float* bias;
  const float* residf;
  unsigned short* outb;
  float* outf;
  unsigned short* out_q;
  unsigned short* out_k;
  int K;
  int tiles_n;
  int ldo;
};

// EPI: 0=QKV scatter(bf16), 1=+resid->f32, 2=relu(+bias)->bf16, 3=+bias+resid->f32
template <int EPI, int TN>
__global__ __launch_bounds__(256) void gemm_bt(GemmP p) {
  constexpr int NFR = TN / 32;  // n-frags per wave
  __shared__ unsigned short As[2][128 * 32];
  __shared__ unsigned short Bs[2][TN * 32];
  const int tid = threadIdx.x;
  const int wave = tid >> 6, lane = tid & 63;
  const int wm = wave >> 1, wn = wave & 1;
  const int bid = xcd_swz(blockIdx.x, gridDim.x);
  const int tn = bid % p.tiles_n, tm = bid / p.tiles_n;
  const int K = p.K;
  const unsigned short* Ab = p.A + (size_t)tm * 128 * K;
  const unsigned short* Bb = p.Bw + (size_t)tn * TN * K;
  f32x4 acc[4][NFR];
#pragma unroll
  for (int i = 0; i < 4; i++)
#pragma unroll
    for (int j = 0; j < NFR; j++) acc[i][j] = (f32x4){0.f, 0.f, 0.f, 0.f};

  const int l15 = lane & 15;
  const int srow = lane >> 2;
  const int scol = (((lane & 3) ^ ((srow >> 1) & 3))) * 8;  // source-swizzled chunk
  auto stage = [&](int buf, int kt) {
#pragma unroll
    for (int i = 0; i < 2; i++) {
      const int r = wave * 32 + i * 16;
      gld_lds16(Ab + (size_t)(r + srow) * K + kt + scol, &As[buf][r * 32]);
    }
    if (TN == 128) {
#pragma unroll
      for (int i = 0; i < 2; i++) {
        const int r = wave * 32 + i * 16;
        gld_lds16(Bb + (size_t)(r + srow) * K + kt + scol, &Bs[buf][r * 32]);
      }
    } else {
      const int r = wave * 16;
      gld_lds16(Bb + (size_t)(r + srow) * K + kt + scol, &Bs[buf][r * 32]);
    }
  };

  stage(0, 0);
  __syncthreads();  // buf0 ready
  const int nIter = K >> 5;
  const int rchunk = (((lane >> 4) ^ ((l15 >> 1) & 3))) * 8;  // swizzled read slot
  for (int it = 0; it < nIter; it++) {
    const int buf = it & 1;
    if (it + 1 < nIter) stage(buf ^ 1, (it + 1) * 32);  // overlap with compute
    bf16x8 af[4], bfr[NFR];
#pragma unroll
    for (int m = 0; m < 4; m++)
      af[m] = *(const bf16x8*)&As[buf][(wm * 64 + m * 16 + l15) * 32 + rchunk];
#pragma unroll
    for (int n = 0; n < NFR; n++)
      bfr[n] = *(const bf16x8*)&Bs[buf][(wn * (TN / 2) + n * 16 + l15) * 32 + rchunk];
#pragma unroll
    for (int m = 0; m < 4; m++)
#pragma unroll
      for (int n = 0; n < NFR; n++)
        acc[m][n] = __builtin_amdgcn_mfma_f32_16x16x32_bf16(af[m], bfr[n], acc[m][n], 0, 0, 0);
    __syncthreads();  // next buf staged + all waves done reading this buf
  }

  const int r0 = tm * 128 + wm * 64;
  const int c0 = tn * TN + wn * (TN / 2);
#pragma unroll
  for (int m = 0; m < 4; m++) {
#pragma unroll
    for (int n = 0; n < NFR; n++) {
#pragma unroll
      for (int rr = 0; rr < 4; rr++) {
        const int row = r0 + m * 16 + (lane >> 4) * 4 + rr;
        const int col = c0 + n * 16 + (lane & 15);
        float v = acc[m][n][rr];
        if (EPI == 0) {
          v += p.bias[col];
          const int h = col / 192, j = col % 192;
          const int bb = row >> 9, nn = row & 511;
          const size_t base = (((size_t)bb * H_ + h) * N_ + nn) * DH_;
          if (j < 64)       p.outb [base + j]        = f2b(v);            // V
          else if (j < 128) p.out_q[base + j - 64]   = f2b(v * 0.125f);   // Q (scale folded)
          else              p.out_k[base + j - 128]  = f2b(v);            // K
        } else if (EPI == 1) {
          p.outf[(size_t)row * p.ldo + col] = v + p.residf[(size_t)row * p.ldo + col];
        } else if (EPI == 2) {
          v += p.bias[col];
          v = v > 0.f ? v : 0.f;
          p.outb[(size_t)row * p.ldo + col] = f2b(v);
        } else {
          p.outf[(size_t)row * p.ldo + col] =
              v + p.bias[col] + p.residf[(size_t)row * p.ldo + col];
        }
      }
    }
  }
}

// ---------------- V transpose: V[b][h][n][d] -> Vt[b][h][d][n] (bf16) ----------------
__global__ __launch_bounds__(256) void transp_v(const unsigned short* __restrict__ V,
                                                unsigned short* __restrict__ Vt) {
  __shared__ unsigned short t[64][65];
  const int bid = blockIdx.x;
  const int bh = bid >> 3, nt = bid & 7;
  const int n0 = nt * 64;
  const int tid = threadIdx.x;
  const unsigned short* src = V + ((size_t)bh * N_ + n0) * DH_;
  {
    const int r = tid >> 2, c = (tid & 3) * 16;
    us8 a = *(const us8*)(src + (size_t)r * DH_ + c);
    us8 b8 = *(const us8*)(src + (size_t)r * DH_ + c + 8);
#pragma unroll
    for (int i = 0; i < 8; i++) { t[r][c + i] = a[i]; t[r][c + 8 + i] = b8[i]; }
  }
  __syncthreads();
  {
    const int d = tid >> 2, nc = (tid & 3) * 16;
    us8 o1, o2;
#pragma unroll
    for (int i = 0; i < 8; i++) { o1[i] = t[nc + i][d]; o2[i] = t[nc + 8 + i][d]; }
    unsigned short* dst = Vt + ((size_t)bh * DH_ + d) * N_ + n0 + nc;
    *(us8*)dst = o1;
    *(us8*)(dst + 8) = o2;
  }
}

// ---------------- Fused flash attention ----------------
__global__ __launch_bounds__(256, 3) void attn_kernel(
    const unsigned short* __restrict__ Qs, const unsigned short* __restrict__ Ks,
    const unsigned short* __restrict__ Vt, const unsigned int* __restrict__ packed,
    unsigned short* __restrict__ attn_out) {
  __shared__ unsigned short Kt[64 * 64];    // [ki][d], chunk-XOR-swizzled
  __shared__ unsigned short Vtt[64 * 64];   // [d][ki], chunk-XOR-swizzled

  const int bid = xcd_swz(blockIdx.x, gridDim.x);
  const int qt = bid & 7, h = (bid >> 3) & 7, b = bid >> 6;
  const int q0 = qt * 64;
  const int tid = threadIdx.x, wave = tid >> 6, lane = tid & 63;
  const int q = lane & 15, hi = lane >> 4;

  const int q_g = q0 + wave * 16 + q;  // this lane's q row
  const size_t bh = (size_t)b * H_ + h;
  const unsigned short* Qb = Qs + (bh * N_ + q_g) * DH_;
  bf16x8 qf[2];
  qf[0] = *(const bf16x8*)(Qb + hi * 8);
  qf[1] = *(const bf16x8*)(Qb + 32 + hi * 8);

  const unsigned short* Kb = Ks + bh * N_ * DH_;
  const unsigned short* Vb = Vt + bh * DH_ * N_;
  const unsigned int* Pbase = packed + (size_t)b * N_ * N_ + q_g;

  f32x4 o[4];
#pragma unroll
  for (int i = 0; i < 4; i++) o[i] = (f32x4){0.f, 0.f, 0.f, 0.f};
  float dsum = 0.f;

  const int str = tid >> 2;
  const int stc = tid & 3;

  us8 pk0, pk1, pv0, pv1;
  unsigned int ppw[16];

  auto load_tile = [&](int kt) {
    const unsigned short* Kp = Kb + (size_t)(kt + str) * DH_ + stc * 16;
    const unsigned short* Vp = Vb + (size_t)str * N_ + kt + stc * 16;
    pk0 = *(const us8*)Kp;
    pk1 = *(const us8*)(Kp + 8);
    pv0 = *(const us8*)Vp;
    pv1 = *(const us8*)(Vp + 8);
    const unsigned int* Pp = Pbase + (size_t)(kt + hi * 4) * N_;
#pragma unroll
    for (int c = 0; c < 4; c++)
#pragma unroll
      for (int j = 0; j < 4; j++)
        ppw[c * 4 + j] = Pp[(size_t)(c * 16 + j) * N_];
  };

  load_tile(0);

  for (int kt = 0; kt < N_; kt += 64) {
    __syncthreads();  // all waves done reading previous tile's LDS
    {
      const int c0 = (stc * 2) ^ (str & 7);
      const int c1 = (stc * 2 + 1) ^ (str & 7);
      *(us8*)&Kt[str * 64 + c0 * 8] = pk0;
      *(us8*)&Kt[str * 64 + c1 * 8] = pk1;
      *(us8*)&Vtt[str * 64 + c0 * 8] = pv0;
      *(us8*)&Vtt[str * 64 + c1 * 8] = pv1;
    }
    unsigned int cpw[16];
#pragma unroll
    for (int i = 0; i < 16; i++) cpw[i] = ppw[i];
    __syncthreads();
    if (kt + 64 < N_) load_tile(kt + 64);

    // --- S^T = K * Q^T (Q pre-scaled by 1/8): C[ki][q], col=q, row=hi*4+r ---
    f32x4 s4[4];
#pragma unroll
    for (int c = 0; c < 4; c++) {
      f32x4 a = (f32x4){0.f, 0.f, 0.f, 0.f};
#pragma unroll
      for (int kd = 0; kd < 2; kd++) {
        const int krow = c * 16 + q;
        const int chunk = (kd * 4 + hi) ^ (q & 7);
        bf16x8 kf = *(const bf16x8*)&Kt[krow * 64 + chunk * 8];
        a = __builtin_amdgcn_mfma_f32_16x16x32_bf16(kf, qf[kd], a, 0, 0, 0);
      }
      s4[c] = a;
    }

    // --- softmax: pj = exp(s)*E (denominator), pm = exp(s)*Em (numerator) ---
    unsigned int pkk[4][2];
#pragma unroll
    for (int c = 0; c < 4; c++) {
      float pm[4];
#pragma unroll
      for (int r = 0; r < 4; r++) {
        const float es = __expf(s4[c][r]);
        const unsigned int w = cpw[c * 4 + r];
        dsum += es * b2f((unsigned short)(w & 0xffffu));
        pm[r] = es * b2f((unsigned short)(w >> 16));
      }
      pkk[c][0] = (unsigned int)f2b(pm[0]) | ((unsigned int)f2b(pm[1]) << 16);
      pkk[c][1] = (unsigned int)f2b(pm[2]) | ((unsigned int)f2b(pm[3]) << 16);
    }

    // --- O^T += V^T * P^T : A=Vt rows (lane-local), B=P (registers) ---
#pragma unroll
    for (int dc = 0; dc < 4; dc++) {
      const int vrow = dc * 16 + q;
#pragma unroll
      for (int t = 0; t < 2; t++) {
        u32x4 pb = {pkk[t][0], pkk[t][1], pkk[t + 2][0], pkk[t + 2][1]};
        bf16x8 pf = __builtin_bit_cast(bf16x8, pb);
        const int ch1 = (2 * t + (hi >> 1)) ^ (vrow & 7);
        const int ch2 = (2 * t + 4 + (hi >> 1)) ^ (vrow & 7);
        us4 v1 = *(const us4*)&Vtt[vrow * 64 + ch1 * 8 + (hi & 1) * 4];
        us4 v2 = *(const us4*)&Vtt[vrow * 64 + ch2 * 8 + (hi & 1) * 4];
        us8 vv;
#pragma unroll
        for (int i = 0; i < 4; i++) { vv[i] = v1[i]; vv[4 + i] = v2[i]; }
        bf16x8 vf = __builtin_bit_cast(bf16x8, vv);
        o[dc] = __builtin_amdgcn_mfma_f32_16x16x32_bf16(vf, pf, o[dc], 0, 0, 0);
      }
    }
  }

  // denominator: sum across the 4 hi-groups sharing this q
  dsum += __shfl_xor(dsum, 16);
  dsum += __shfl_xor(dsum, 32);
  const float inv = 1.f / dsum;

  const size_t obase = ((size_t)b * N_ + q_g) * DM_ + h * DH_ + hi * 4;
#pragma unroll
  for (int dc = 0; dc < 4; dc++) {
    us4 ov;
#pragma unroll
    for (int r = 0; r < 4; r++) {
      float val = o[dc][r] * inv;
      val = val >= 0.f ? val : 0.01f * val;  // leaky_relu fused
      ov[r] = f2b(val);
    }
    *(us4*)&attn_out[obase + dc * 16] = ov;
  }
}

extern "C" void kernel_launch(void* const* d_in, const int* in_sizes, int n_in,
                              void* d_out, int out_size, void* d_ws, size_t ws_size,
                              hipStream_t stream) {
  const float* Z     = (const float*)d_in[0];
  const float* D     = (const float*)d_in[1];
  const float* nm    = (const float*)d_in[2];
  const float* mask  = (const float*)d_in[3];
  const float* gamma = (const float*)d_in[4];
  const float* qkv_w = (const float*)d_in[5];
  const float* qkv_b = (const float*)d_in[6];
  const float* o_w   = (const float*)d_in[7];
  const float* ln1_w = (const float*)d_in[8];
  const float* ln1_b = (const float*)d_in[9];
  const float* ln2_w = (const float*)d_in[10];
  const float* ln2_b = (const float*)d_in[11];
  const float* p1_w  = (const float*)d_in[12];
  const float* p1_b  = (const float*)d_in[13];
  const float* p2_w  = (const float*)d_in[14];
  const float* p2_b  = (const float*)d_in[15];
  const int* ra = (const int*)d_in[16];
  const int* rb = (const int*)d_in[17];
  float* out = (float*)d_out;

  const size_t SZ = (size_t)16384 * 512;  // elements per (B*N, DM) buffer
  unsigned short* buf0  = (unsigned short*)d_ws;  // Zn -> attn_act -> Zn2 (bf16)
  unsigned short* bufQ  = buf0 + SZ;
  unsigned short* bufK  = bufQ + SZ;
  unsigned short* bufV  = bufK + SZ;
  unsigned short* bufVt = bufV + SZ;
  float* bufZ = (float*)(bufVt + SZ);             // residual stream (f32, SZ floats)
  unsigned short* bufH = bufQ;                    // FFN hidden reuses Q/K/V/Vt span
  unsigned int* packed = (unsigned int*)bufZ;     // packed E/Em reuses bufZ span
  unsigned short* wQKV = (unsigned short*)(bufZ + SZ);
  unsigned short* wO   = wQKV + (size_t)3 * DM_ * DM_;
  unsigned short* wP1  = wO + (size_t)DM_ * DM_;
  unsigned short* wP2  = wP1 + (size_t)DI_ * DM_;

  // 0. fused prologue: prep_sm (2048) + conv_w (1536) + LN1 (4096)
  fused_pre<<<7680, 256, 0, stream>>>(D, nm, mask, gamma, ra, rb, packed,
                                      qkv_w, o_w, p1_w, p2_w, wQKV, wO, wP1, wP2,
                                      Z, ln1_w, ln1_b, buf0);

  // 2. QKV projection (TM=128, TN=64, grid 3072)
  GemmP p1{};
  p1.A = buf0; p1.Bw = wQKV; p1.bias = qkv_b;
  p1.outb = bufV; p1.out_q = bufQ; p1.out_k = bufK;
  p1.K = 512; p1.tiles_n = 24; p1.ldo = 0;
  gemm_bt<0, 64><<<128 * 24, 256, 0, stream>>>(p1);

  // 3. V transpose
  transp_v<<<2048, 256, 0, stream>>>(bufV, bufVt);

  // 4. Fused attention (incl. leaky_relu)
  attn_kernel<<<B_ * H_ * 8, 256, 0, stream>>>(bufQ, bufK, bufVt, packed, buf0);

  // 5. Output projection + residual (TN=64, grid 1024)
  GemmP p3{};
  p3.A = buf0; p3.Bw = wO; p3.residf = Z; p3.outf = bufZ;
  p3.K = 512; p3.tiles_n = 8; p3.ldo = 512;
  gemm_bt<1, 64><<<128 * 8, 256, 0, stream>>>(p3);

  // 6. LN2 (f32 -> bf16)
  ln_kernel<<<4096, 256, 0, stream>>>(bufZ, ln2_w, ln2_b, buf0);

  // 7. FFN up + relu (TN=128, grid 2048)
  GemmP p5{};
  p5.A = buf0; p5.Bw = wP1; p5.bias = p1_b; p5.outb = bufH;
  p5.K = 512; p5.tiles_n = 16; p5.ldo = 2048;
  gemm_bt<2, 128><<<128 * 16, 256, 0, stream>>>(p5);

  // 8. FFN down + bias + residual -> out (TN=64, grid 1024)
  GemmP p6{};
  p6.A = bufH; p6.Bw = wP2; p6.bias = p2_b; p6.residf = bufZ; p6.outf = out;
  p6.K = 2048; p6.tiles_n = 8; p6.ldo = 512;
  gemm_bt<3, 64><<<128 * 8, 256, 0, stream>>>(p6);
}

// Round 22
// 266.486 us; speedup vs baseline: 1.1052x; 1.0327x over previous
//
#include <hip/hip_runtime.h>
#include <hip/hip_bf16.h>

// Problem constants
#define B_  32
#define N_  512
#define DM_ 512
#define H_  8
#define DH_ 64
#define DI_ 2048

typedef __attribute__((ext_vector_type(8))) __bf16 bf16x8;
typedef __attribute__((ext_vector_type(4))) float f32x4;
typedef __attribute__((ext_vector_type(8))) unsigned short us8;
typedef __attribute__((ext_vector_type(4))) unsigned short us4;
typedef __attribute__((ext_vector_type(4))) unsigned int u32x4;

typedef __attribute__((address_space(1))) const void g_cvoid;
typedef __attribute__((address_space(3))) void l_void;

__device__ __forceinline__ float b2f(unsigned short u) {
  union { unsigned int i; float f; } x; x.i = ((unsigned int)u) << 16; return x.f;
}
__device__ __forceinline__ unsigned short f2b(float f) {
  union { float f; unsigned int i; } x; x.f = f;
  unsigned int r = x.i + 0x7FFFu + ((x.i >> 16) & 1u);
  return (unsigned short)(r >> 16);
}
__device__ __forceinline__ void gld_lds16(const unsigned short* g, unsigned short* l) {
  __builtin_amdgcn_global_load_lds((g_cvoid*)g, (l_void*)l, 16, 0, 0);
}
// bijective XCD swizzle for grids with nwg % 8 == 0
__device__ __forceinline__ int xcd_swz(int bid, int nwg) {
  return (bid & 7) * (nwg >> 3) + (bid >> 3);
}

// ---------------- fused prologue: prep_sm (2048 blocks) + conv_w (1536) + LN1 (4096) ----------------
__global__ __launch_bounds__(256) void fused_pre(
    const float* __restrict__ Dg, const float* __restrict__ nmg,
    const float* __restrict__ mkg, const float* __restrict__ gammaf,
    const int* __restrict__ ra, const int* __restrict__ rb,
    unsigned int* __restrict__ packed,
    const float* __restrict__ wa, const float* __restrict__ wb,
    const float* __restrict__ wc, const float* __restrict__ wd,
    unsigned short* __restrict__ oa, unsigned short* __restrict__ ob,
    unsigned short* __restrict__ oc, unsigned short* __restrict__ od,
    const float* __restrict__ x, const float* __restrict__ lw,
    const float* __restrict__ lb, unsigned short* __restrict__ y) {
  __shared__ unsigned int t[64][65];
  const int blk = blockIdx.x;
  const int tid = threadIdx.x;
  if (blk < 2048) {
    // ---- prep_sm: E=exp(nm-gamma*D), Em=E*mask, packed [b][ki][q] ----
    const int kt = blk & 7, qt = (blk >> 3) & 7, b = blk >> 6;
    const int ra_e = *ra, rb_e = *rb;
    const int r = tid >> 2;
    const int c = (tid & 3) * 16;
    const int q_g = qt * 64 + r;
    const int rq = (q_g >= ra_e) + (q_g >= rb_e);
    const float g0 = gammaf[rq * 4], g1 = gammaf[rq * 4 + 1], g2 = gammaf[rq * 4 + 2];
    const size_t base = ((size_t)b * N_ + q_g) * N_ + kt * 64 + c;
#pragma unroll
    for (int i = 0; i < 4; i++) {
      f32x4 dv = *(const f32x4*)(Dg + base + i * 4);
      f32x4 nv = *(const f32x4*)(nmg + base + i * 4);
      f32x4 mv = *(const f32x4*)(mkg + base + i * 4);
#pragma unroll
      for (int j = 0; j < 4; j++) {
        const int gk = kt * 64 + c + i * 4 + j;
        const float g = gk >= rb_e ? g2 : (gk >= ra_e ? g1 : g0);
        const float E = __expf(nv[j] - g * dv[j]);
        const float Em = E * mv[j];
        t[r][c + i * 4 + j] = (unsigned int)f2b(E) | ((unsigned int)f2b(Em) << 16);
      }
    }
    __syncthreads();
    const int rr = tid >> 2;
    const int cc = (tid & 3) * 16;
    unsigned int* dst = packed + ((size_t)b * N_ + kt * 64 + rr) * N_ + qt * 64 + cc;
#pragma unroll
    for (int i = 0; i < 4; i++) {
      u32x4 v;
#pragma unroll
      for (int j = 0; j < 4; j++) v[j] = t[cc + i * 4 + j][rr];
      *(u32x4*)(dst + i * 4) = v;
    }
  } else if (blk < 3584) {
    // ---- conv_w: f32 -> bf16 weight conversion ----
    const int bid = blk - 2048;
    const float* src; unsigned short* dst; int idx;
    if (bid < 384)       { src = wa; dst = oa; idx = bid; }
    else if (bid < 512)  { src = wb; dst = ob; idx = bid - 384; }
    else if (bid < 1024) { src = wc; dst = oc; idx = bid - 512; }
    else                 { src = wd; dst = od; idx = bid - 1024; }
    const int off = idx * 2048 + tid * 8;
    f32x4 x0 = *(const f32x4*)(src + off);
    f32x4 x1 = *(const f32x4*)(src + off + 4);
    us8 o;
#pragma unroll
    for (int i = 0; i < 4; i++) { o[i] = f2b(x0[i]); o[4 + i] = f2b(x1[i]); }
    *(us8*)(dst + off) = o;
  } else {
    // ---- LN1: f32 -> bf16, one wave per row ----
    const int row  = (blk - 3584) * 4 + (tid >> 6);
    const int lane = tid & 63;
    const float* xr = x + (size_t)row * DM_ + lane * 8;
    f32x4 x0 = *(const f32x4*)xr;
    f32x4 x1 = *(const f32x4*)(xr + 4);
    float v[8]; float s = 0.f;
#pragma unroll
    for (int i = 0; i < 4; i++) { v[i] = x0[i]; v[4 + i] = x1[i]; }
#pragma unroll
    for (int i = 0; i < 8; i++) s += v[i];
#pragma unroll
    for (int o = 1; o < 64; o <<= 1) s += __shfl_xor(s, o);
    const float mu = s * (1.f / DM_);
    float q = 0.f;
#pragma unroll
    for (int i = 0; i < 8; i++) { float d = v[i] - mu; q += d * d; }
#pragma unroll
    for (int o = 1; o < 64; o <<= 1) q += __shfl_xor(q, o);
    const float rstd = rsqrtf(q * (1.f / DM_) + 1e-5f);
    f32x4 w0 = *(const f32x4*)(lw + lane * 8);
    f32x4 w1 = *(const f32x4*)(lw + lane * 8 + 4);
    f32x4 b0 = *(const f32x4*)(lb + lane * 8);
    f32x4 b1 = *(const f32x4*)(lb + lane * 8 + 4);
    us8 out;
#pragma unroll
    for (int i = 0; i < 4; i++) {
      out[i]     = f2b((v[i] - mu) * rstd * w0[i] + b0[i]);
      out[4 + i] = f2b((v[4 + i] - mu) * rstd * w1[i] + b1[i]);
    }
    *(us8*)(y + (size_t)row * DM_ + lane * 8) = out;
  }
}

// ---------------- LayerNorm (bf16 in, bf16 out): one wave per row of 512 ----------------
__global__ __launch_bounds__(256) void ln_kernel(const unsigned short* __restrict__ x,
                                                 const float* __restrict__ w,
                                                 const float* __restrict__ b,
                                                 unsigned short* __restrict__ y) {
  const int row  = blockIdx.x * 4 + (threadIdx.x >> 6);
  const int lane = threadIdx.x & 63;
  us8 raw = *(const us8*)(x + (size_t)row * DM_ + lane * 8);
  float v[8]; float s = 0.f;
#pragma unroll
  for (int i = 0; i < 8; i++) { v[i] = b2f(raw[i]); s += v[i]; }
#pragma unroll
  for (int o = 1; o < 64; o <<= 1) s += __shfl_xor(s, o);
  const float mu = s * (1.f / DM_);
  float q = 0.f;
#pragma unroll
  for (int i = 0; i < 8; i++) { float d = v[i] - mu; q += d * d; }
#pragma unroll
  for (int o = 1; o < 64; o <<= 1) q += __shfl_xor(q, o);
  const float rstd = rsqrtf(q * (1.f / DM_) + 1e-5f);
  f32x4 w0 = *(const f32x4*)(w + lane * 8);
  f32x4 w1 = *(const f32x4*)(w + lane * 8 + 4);
  f32x4 b0 = *(const f32x4*)(b + lane * 8);
  f32x4 b1 = *(const f32x4*)(b + lane * 8 + 4);
  us8 out;
#pragma unroll
  for (int i = 0; i < 4; i++) {
    out[i]     = f2b((v[i] - mu) * rstd * w0[i] + b0[i]);
    out[4 + i] = f2b((v[4 + i] - mu) * rstd * w1[i] + b1[i]);
  }
  *(us8*)(y + (size_t)row * DM_ + lane * 8) = out;
}

// ---------------- GEMM: C = A(MxK,bf16) * B(NxK,bf16)^T, 128xTN tile, BK=32 ----------------
// 2-phase double-buffered LDS pipeline; R9-exact epilogue; 4-chunk XOR source
// swizzle (bank conflicts = 0, R14-verified). Residual stream stored bf16.
struct GemmP {
  const unsigned short* A;
  const unsigned short* Bw;
  const float* bias;
  const float* residf;          // f32 resid (o-proj reads input Z)
  const unsigned short* residb; // bf16 resid (FFN2 reads bufZb)
  unsigned short* outb;
  float* outf;
  unsigned short* out_q;
  unsigned short* out_k;
  int K;
  int tiles_n;
  int ldo;
};

// EPI: 0=QKV scatter(bf16), 1=+resid(f32)->bf16, 2=relu(+bias)->bf16, 3=+bias+resid(bf16)->f32
template <int EPI, int TN>
__global__ __launch_bounds__(256) void gemm_bt(GemmP p) {
  constexpr int NFR = TN / 32;  // n-frags per wave
  __shared__ unsigned short As[2][128 * 32];
  __shared__ unsigned short Bs[2][TN * 32];
  const int tid = threadIdx.x;
  const int wave = tid >> 6, lane = tid & 63;
  const int wm = wave >> 1, wn = wave & 1;
  const int bid = xcd_swz(blockIdx.x, gridDim.x);
  const int tn = bid % p.tiles_n, tm = bid / p.tiles_n;
  const int K = p.K;
  const unsigned short* Ab = p.A + (size_t)tm * 128 * K;
  const unsigned short* Bb = p.Bw + (size_t)tn * TN * K;
  f32x4 acc[4][NFR];
#pragma unroll
  for (int i = 0; i < 4; i++)
#pragma unroll
    for (int j = 0; j < NFR; j++) acc[i][j] = (f32x4){0.f, 0.f, 0.f, 0.f};

  const int l15 = lane & 15;
  const int srow = lane >> 2;
  const int scol = (((lane & 3) ^ ((srow >> 1) & 3))) * 8;  // source-swizzled chunk
  auto stage = [&](int buf, int kt) {
#pragma unroll
    for (int i = 0; i < 2; i++) {
      const int r = wave * 32 + i * 16;
      gld_lds16(Ab + (size_t)(r + srow) * K + kt + scol, &As[buf][r * 32]);
    }
    if (TN == 128) {
#pragma unroll
      for (int i = 0; i < 2; i++) {
        const int r = wave * 32 + i * 16;
        gld_lds16(Bb + (size_t)(r + srow) * K + kt + scol, &Bs[buf][r * 32]);
      }
    } else {
      const int r = wave * 16;
      gld_lds16(Bb + (size_t)(r + srow) * K + kt + scol, &Bs[buf][r * 32]);
    }
  };

  stage(0, 0);
  __syncthreads();  // buf0 ready
  const int nIter = K >> 5;
  const int rchunk = (((lane >> 4) ^ ((l15 >> 1) & 3))) * 8;  // swizzled read slot
  for (int it = 0; it < nIter; it++) {
    const int buf = it & 1;
    if (it + 1 < nIter) stage(buf ^ 1, (it + 1) * 32);  // overlap with compute
    bf16x8 af[4], bfr[NFR];
#pragma unroll
    for (int m = 0; m < 4; m++)
      af[m] = *(const bf16x8*)&As[buf][(wm * 64 + m * 16 + l15) * 32 + rchunk];
#pragma unroll
    for (int n = 0; n < NFR; n++)
      bfr[n] = *(const bf16x8*)&Bs[buf][(wn * (TN / 2) + n * 16 + l15) * 32 + rchunk];
#pragma unroll
    for (int m = 0; m < 4; m++)
#pragma unroll
      for (int n = 0; n < NFR; n++)
        acc[m][n] = __builtin_amdgcn_mfma_f32_16x16x32_bf16(af[m], bfr[n], acc[m][n], 0, 0, 0);
    __syncthreads();  // next buf staged + all waves done reading this buf
  }

  const int r0 = tm * 128 + wm * 64;
  const int c0 = tn * TN + wn * (TN / 2);
#pragma unroll
  for (int m = 0; m < 4; m++) {
#pragma unroll
    for (int n = 0; n < NFR; n++) {
#pragma unroll
      for (int rr = 0; rr < 4; rr++) {
        const int row = r0 + m * 16 + (lane >> 4) * 4 + rr;
        const int col = c0 + n * 16 + (lane & 15);
        float v = acc[m][n][rr];
        if (EPI == 0) {
          v += p.bias[col];
          const int h = col / 192, j = col % 192;
          const int bb = row >> 9, nn = row & 511;
          const size_t base = (((size_t)bb * H_ + h) * N_ + nn) * DH_;
          if (j < 64)       p.outb [base + j]        = f2b(v);            // V
          else if (j < 128) p.out_q[base + j - 64]   = f2b(v * 0.125f);   // Q (scale folded)
          else              p.out_k[base + j - 128]  = f2b(v);            // K
        } else if (EPI == 1) {
          p.outb[(size_t)row * p.ldo + col] =
              f2b(v + p.residf[(size_t)row * p.ldo + col]);
        } else if (EPI == 2) {
          v += p.bias[col];
          v = v > 0.f ? v : 0.f;
          p.outb[(size_t)row * p.ldo + col] = f2b(v);
        } else {
          p.outf[(size_t)row * p.ldo + col] =
              v + p.bias[col] + b2f(p.residb[(size_t)row * p.ldo + col]);
        }
      }
    }
  }
}

// ---------------- V transpose: V[b][h][n][d] -> Vt[b][h][d][n] (bf16) ----------------
__global__ __launch_bounds__(256) void transp_v(const unsigned short* __restrict__ V,
                                                unsigned short* __restrict__ Vt) {
  __shared__ unsigned short t[64][65];
  const int bid = blockIdx.x;
  const int bh = bid >> 3, nt = bid & 7;
  const int n0 = nt * 64;
  const int tid = threadIdx.x;
  const unsigned short* src = V + ((size_t)bh * N_ + n0) * DH_;
  {
    const int r = tid >> 2, c = (tid & 3) * 16;
    us8 a = *(const us8*)(src + (size_t)r * DH_ + c);
    us8 b8 = *(const us8*)(src + (size_t)r * DH_ + c + 8);
#pragma unroll
    for (int i = 0; i < 8; i++) { t[r][c + i] = a[i]; t[r][c + 8 + i] = b8[i]; }
  }
  __syncthreads();
  {
    const int d = tid >> 2, nc = (tid & 3) * 16;
    us8 o1, o2;
#pragma unroll
    for (int i = 0; i < 8; i++) { o1[i] = t[nc + i][d]; o2[i] = t[nc + 8 + i][d]; }
    unsigned short* dst = Vt + ((size_t)bh * DH_ + d) * N_ + n0 + nc;
    *(us8*)dst = o1;
    *(us8*)(dst + 8) = o2;
  }
}

// ---------------- Fused flash attention ----------------
__global__ __launch_bounds__(256, 3) void attn_kernel(
    const unsigned short* __restrict__ Qs, const unsigned short* __restrict__ Ks,
    const unsigned short* __restrict__ Vt, const unsigned int* __restrict__ packed,
    unsigned short* __restrict__ attn_out) {
  __shared__ unsigned short Kt[64 * 64];    // [ki][d], chunk-XOR-swizzled
  __shared__ unsigned short Vtt[64 * 64];   // [d][ki], chunk-XOR-swizzled

  const int bid = xcd_swz(blockIdx.x, gridDim.x);
  const int qt = bid & 7, h = (bid >> 3) & 7, b = bid >> 6;
  const int q0 = qt * 64;
  const int tid = threadIdx.x, wave = tid >> 6, lane = tid & 63;
  const int q = lane & 15, hi = lane >> 4;

  const int q_g = q0 + wave * 16 + q;  // this lane's q row
  const size_t bh = (size_t)b * H_ + h;
  const unsigned short* Qb = Qs + (bh * N_ + q_g) * DH_;
  bf16x8 qf[2];
  qf[0] = *(const bf16x8*)(Qb + hi * 8);
  qf[1] = *(const bf16x8*)(Qb + 32 + hi * 8);

  const unsigned short* Kb = Ks + bh * N_ * DH_;
  const unsigned short* Vb = Vt + bh * DH_ * N_;
  const unsigned int* Pbase = packed + (size_t)b * N_ * N_ + q_g;

  f32x4 o[4];
#pragma unroll
  for (int i = 0; i < 4; i++) o[i] = (f32x4){0.f, 0.f, 0.f, 0.f};
  float dsum = 0.f;

  const int str = tid >> 2;
  const int stc = tid & 3;

  us8 pk0, pk1, pv0, pv1;
  unsigned int ppw[16];

  auto load_tile = [&](int kt) {
    const unsigned short* Kp = Kb + (size_t)(kt + str) * DH_ + stc * 16;
    const unsigned short* Vp = Vb + (size_t)str * N_ + kt + stc * 16;
    pk0 = *(const us8*)Kp;
    pk1 = *(const us8*)(Kp + 8);
    pv0 = *(const us8*)Vp;
    pv1 = *(const us8*)(Vp + 8);
    const unsigned int* Pp = Pbase + (size_t)(kt + hi * 4) * N_;
#pragma unroll
    for (int c = 0; c < 4; c++)
#pragma unroll
      for (int j = 0; j < 4; j++)
        ppw[c * 4 + j] = Pp[(size_t)(c * 16 + j) * N_];
  };

  load_tile(0);

  for (int kt = 0; kt < N_; kt += 64) {
    __syncthreads();  // all waves done reading previous tile's LDS
    {
      const int c0 = (stc * 2) ^ (str & 7);
      const int c1 = (stc * 2 + 1) ^ (str & 7);
      *(us8*)&Kt[str * 64 + c0 * 8] = pk0;
      *(us8*)&Kt[str * 64 + c1 * 8] = pk1;
      *(us8*)&Vtt[str * 64 + c0 * 8] = pv0;
      *(us8*)&Vtt[str * 64 + c1 * 8] = pv1;
    }
    unsigned int cpw[16];
#pragma unroll
    for (int i = 0; i < 16; i++) cpw[i] = ppw[i];
    __syncthreads();
    if (kt + 64 < N_) load_tile(kt + 64);

    // --- S^T = K * Q^T (Q pre-scaled by 1/8): C[ki][q], col=q, row=hi*4+r ---
    f32x4 s4[4];
#pragma unroll
    for (int c = 0; c < 4; c++) {
      f32x4 a = (f32x4){0.f, 0.f, 0.f, 0.f};
#pragma unroll
      for (int kd = 0; kd < 2; kd++) {
        const int krow = c * 16 + q;
        const int chunk = (kd * 4 + hi) ^ (q & 7);
        bf16x8 kf = *(const bf16x8*)&Kt[krow * 64 + chunk * 8];
        a = __builtin_amdgcn_mfma_f32_16x16x32_bf16(kf, qf[kd], a, 0, 0, 0);
      }
      s4[c] = a;
    }

    // --- softmax: pj = exp(s)*E (denominator), pm = exp(s)*Em (numerator) ---
    unsigned int pkk[4][2];
#pragma unroll
    for (int c = 0; c < 4; c++) {
      float pm[4];
#pragma unroll
      for (int r = 0; r < 4; r++) {
        const float es = __expf(s4[c][r]);
        const unsigned int w = cpw[c * 4 + r];
        dsum += es * b2f((unsigned short)(w & 0xffffu));
        pm[r] = es * b2f((unsigned short)(w >> 16));
      }
      pkk[c][0] = (unsigned int)f2b(pm[0]) | ((unsigned int)f2b(pm[1]) << 16);
      pkk[c][1] = (unsigned int)f2b(pm[2]) | ((unsigned int)f2b(pm[3]) << 16);
    }

    // --- O^T += V^T * P^T : A=Vt rows (lane-local), B=P (registers) ---
#pragma unroll
    for (int dc = 0; dc < 4; dc++) {
      const int vrow = dc * 16 + q;
#pragma unroll
      for (int t = 0; t < 2; t++) {
        u32x4 pb = {pkk[t][0], pkk[t][1], pkk[t + 2][0], pkk[t + 2][1]};
        bf16x8 pf = __builtin_bit_cast(bf16x8, pb);
        const int ch1 = (2 * t + (hi >> 1)) ^ (vrow & 7);
        const int ch2 = (2 * t + 4 + (hi >> 1)) ^ (vrow & 7);
        us4 v1 = *(const us4*)&Vtt[vrow * 64 + ch1 * 8 + (hi & 1) * 4];
        us4 v2 = *(const us4*)&Vtt[vrow * 64 + ch2 * 8 + (hi & 1) * 4];
        us8 vv;
#pragma unroll
        for (int i = 0; i < 4; i++) { vv[i] = v1[i]; vv[4 + i] = v2[i]; }
        bf16x8 vf = __builtin_bit_cast(bf16x8, vv);
        o[dc] = __builtin_amdgcn_mfma_f32_16x16x32_bf16(vf, pf, o[dc], 0, 0, 0);
      }
    }
  }

  // denominator: sum across the 4 hi-groups sharing this q
  dsum += __shfl_xor(dsum, 16);
  dsum += __shfl_xor(dsum, 32);
  const float inv = 1.f / dsum;

  const size_t obase = ((size_t)b * N_ + q_g) * DM_ + h * DH_ + hi * 4;
#pragma unroll
  for (int dc = 0; dc < 4; dc++) {
    us4 ov;
#pragma unroll
    for (int r = 0; r < 4; r++) {
      float val = o[dc][r] * inv;
      val = val >= 0.f ? val : 0.01f * val;  // leaky_relu fused
      ov[r] = f2b(val);
    }
    *(us4*)&attn_out[obase + dc * 16] = ov;
  }
}

extern "C" void kernel_launch(void* const* d_in, const int* in_sizes, int n_in,
                              void* d_out, int out_size, void* d_ws, size_t ws_size,
                              hipStream_t stream) {
  const float* Z     = (const float*)d_in[0];
  const float* D     = (const float*)d_in[1];
  const float* nm    = (const float*)d_in[2];
  const float* mask  = (const float*)d_in[3];
  const float* gamma = (const float*)d_in[4];
  const float* qkv_w = (const float*)d_in[5];
  const float* qkv_b = (const float*)d_in[6];
  const float* o_w   = (const float*)d_in[7];
  const float* ln1_w = (const float*)d_in[8];
  const float* ln1_b = (const float*)d_in[9];
  const float* ln2_w = (const float*)d_in[10];
  const float* ln2_b = (const float*)d_in[11];
  const float* p1_w  = (const float*)d_in[12];
  const float* p1_b  = (const float*)d_in[13];
  const float* p2_w  = (const float*)d_in[14];
  const float* p2_b  = (const float*)d_in[15];
  const int* ra = (const int*)d_in[16];
  const int* rb = (const int*)d_in[17];
  float* out = (float*)d_out;

  const size_t SZ = (size_t)16384 * 512;  // elements per (B*N, DM) buffer
  unsigned short* buf0  = (unsigned short*)d_ws;  // Zn -> attn_act -> Zn2 (bf16)
  unsigned short* bufQ  = buf0 + SZ;
  unsigned short* bufK  = bufQ + SZ;
  unsigned short* bufV  = bufK + SZ;
  unsigned short* bufVt = bufV + SZ;
  float* bufZspan = (float*)(bufVt + SZ);         // SZ floats span
  unsigned short* bufZb = (unsigned short*)bufZspan;  // residual stream (bf16)
  unsigned short* bufH = bufQ;                    // FFN hidden reuses Q/K/V/Vt span
  unsigned int* packed = (unsigned int*)bufZspan; // packed E/Em reuses span (consumed
                                                  // by attn before o-proj writes bufZb)
  unsigned short* wQKV = (unsigned short*)(bufZspan + SZ);
  unsigned short* wO   = wQKV + (size_t)3 * DM_ * DM_;
  unsigned short* wP1  = wO + (size_t)DM_ * DM_;
  unsigned short* wP2  = wP1 + (size_t)DI_ * DM_;

  // 0. fused prologue: prep_sm (2048) + conv_w (1536) + LN1 (4096)
  fused_pre<<<7680, 256, 0, stream>>>(D, nm, mask, gamma, ra, rb, packed,
                                      qkv_w, o_w, p1_w, p2_w, wQKV, wO, wP1, wP2,
                                      Z, ln1_w, ln1_b, buf0);

  // 2. QKV projection (TM=128, TN=64, grid 3072)
  GemmP p1{};
  p1.A = buf0; p1.Bw = wQKV; p1.bias = qkv_b;
  p1.outb = bufV; p1.out_q = bufQ; p1.out_k = bufK;
  p1.K = 512; p1.tiles_n = 24; p1.ldo = 0;
  gemm_bt<0, 64><<<128 * 24, 256, 0, stream>>>(p1);

  // 3. V transpose
  transp_v<<<2048, 256, 0, stream>>>(bufV, bufVt);

  // 4. Fused attention (incl. leaky_relu)
  attn_kernel<<<B_ * H_ * 8, 256, 0, stream>>>(bufQ, bufK, bufVt, packed, buf0);

  // 5. Output projection + residual -> bf16 (TN=64, grid 1024)
  GemmP p3{};
  p3.A = buf0; p3.Bw = wO; p3.residf = Z; p3.outb = bufZb;
  p3.K = 512; p3.tiles_n = 8; p3.ldo = 512;
  gemm_bt<1, 64><<<128 * 8, 256, 0, stream>>>(p3);

  // 6. LN2 (bf16 -> bf16)
  ln_kernel<<<4096, 256, 0, stream>>>(bufZb, ln2_w, ln2_b, buf0);

  // 7. FFN up + relu (TN=128, grid 2048)
  GemmP p5{};
  p5.A = buf0; p5.Bw = wP1; p5.bias = p1_b; p5.outb = bufH;
  p5.K = 512; p5.tiles_n = 16; p5.ldo = 2048;
  gemm_bt<2, 128><<<128 * 16, 256, 0, stream>>>(p5);

  // 8. FFN down + bias + resid(bf16) -> out (f32) (TN=64, grid 1024)
  GemmP p6{};
  p6.A = bufH; p6.Bw = wP2; p6.bias = p2_b; p6.residb = bufZb; p6.outf = out;
  p6.K = 2048; p6.tiles_n = 8; p6.ldo = 512;
  gemm_bt<3, 64><<<128 * 8, 256, 0, stream>>>(p6);
}

// Round 23
// 266.383 us; speedup vs baseline: 1.1056x; 1.0004x over previous
//
#include <hip/hip_runtime.h>
#include <hip/hip_bf16.h>

// Problem constants
#define B_  32
#define N_  512
#define DM_ 512
#define H_  8
#define DH_ 64
#define DI_ 2048

typedef __attribute__((ext_vector_type(8))) __bf16 bf16x8;
typedef __attribute__((ext_vector_type(4))) float f32x4;
typedef __attribute__((ext_vector_type(8))) unsigned short us8;
typedef __attribute__((ext_vector_type(4))) unsigned short us4;
typedef __attribute__((ext_vector_type(4))) unsigned int u32x4;

typedef __attribute__((address_space(1))) const void g_cvoid;
typedef __attribute__((address_space(3))) void l_void;

__device__ __forceinline__ float b2f(unsigned short u) {
  union { unsigned int i; float f; } x; x.i = ((unsigned int)u) << 16; return x.f;
}
__device__ __forceinline__ unsigned short f2b(float f) {
  union { float f; unsigned int i; } x; x.f = f;
  unsigned int r = x.i + 0x7FFFu + ((x.i >> 16) & 1u);
  return (unsigned short)(r >> 16);
}
__device__ __forceinline__ void gld_lds16(const unsigned short* g, unsigned short* l) {
  __builtin_amdgcn_global_load_lds((g_cvoid*)g, (l_void*)l, 16, 0, 0);
}
// bijective XCD swizzle for grids with nwg % 8 == 0
__device__ __forceinline__ int xcd_swz(int bid, int nwg) {
  return (bid & 7) * (nwg >> 3) + (bid >> 3);
}

// ---------------- fused prologue: prep_sm (2048 blocks) + conv_w (1536) + LN1 (4096) ----------------
__global__ __launch_bounds__(256) void fused_pre(
    const float* __restrict__ Dg, const float* __restrict__ nmg,
    const float* __restrict__ mkg, const float* __restrict__ gammaf,
    const int* __restrict__ ra, const int* __restrict__ rb,
    unsigned int* __restrict__ packed,
    const float* __restrict__ wa, const float* __restrict__ wb,
    const float* __restrict__ wc, const float* __restrict__ wd,
    unsigned short* __restrict__ oa, unsigned short* __restrict__ ob,
    unsigned short* __restrict__ oc, unsigned short* __restrict__ od,
    const float* __restrict__ x, const float* __restrict__ lw,
    const float* __restrict__ lb, unsigned short* __restrict__ y) {
  __shared__ unsigned int t[64][65];
  const int blk = blockIdx.x;
  const int tid = threadIdx.x;
  if (blk < 2048) {
    // ---- prep_sm: E=exp(nm-gamma*D), Em=E*mask, packed [b][ki][q] ----
    const int kt = blk & 7, qt = (blk >> 3) & 7, b = blk >> 6;
    const int ra_e = *ra, rb_e = *rb;
    const int r = tid >> 2;
    const int c = (tid & 3) * 16;
    const int q_g = qt * 64 + r;
    const int rq = (q_g >= ra_e) + (q_g >= rb_e);
    const float g0 = gammaf[rq * 4], g1 = gammaf[rq * 4 + 1], g2 = gammaf[rq * 4 + 2];
    const size_t base = ((size_t)b * N_ + q_g) * N_ + kt * 64 + c;
#pragma unroll
    for (int i = 0; i < 4; i++) {
      f32x4 dv = *(const f32x4*)(Dg + base + i * 4);
      f32x4 nv = *(const f32x4*)(nmg + base + i * 4);
      f32x4 mv = *(const f32x4*)(mkg + base + i * 4);
#pragma unroll
      for (int j = 0; j < 4; j++) {
        const int gk = kt * 64 + c + i * 4 + j;
        const float g = gk >= rb_e ? g2 : (gk >= ra_e ? g1 : g0);
        const float E = __expf(nv[j] - g * dv[j]);
        const float Em = E * mv[j];
        t[r][c + i * 4 + j] = (unsigned int)f2b(E) | ((unsigned int)f2b(Em) << 16);
      }
    }
    __syncthreads();
    const int rr = tid >> 2;
    const int cc = (tid & 3) * 16;
    unsigned int* dst = packed + ((size_t)b * N_ + kt * 64 + rr) * N_ + qt * 64 + cc;
#pragma unroll
    for (int i = 0; i < 4; i++) {
      u32x4 v;
#pragma unroll
      for (int j = 0; j < 4; j++) v[j] = t[cc + i * 4 + j][rr];
      *(u32x4*)(dst + i * 4) = v;
    }
  } else if (blk < 3584) {
    // ---- conv_w: f32 -> bf16 weight conversion ----
    const int bid = blk - 2048;
    const float* src; unsigned short* dst; int idx;
    if (bid < 384)       { src = wa; dst = oa; idx = bid; }
    else if (bid < 512)  { src = wb; dst = ob; idx = bid - 384; }
    else if (bid < 1024) { src = wc; dst = oc; idx = bid - 512; }
    else                 { src = wd; dst = od; idx = bid - 1024; }
    const int off = idx * 2048 + tid * 8;
    f32x4 x0 = *(const f32x4*)(src + off);
    f32x4 x1 = *(const f32x4*)(src + off + 4);
    us8 o;
#pragma unroll
    for (int i = 0; i < 4; i++) { o[i] = f2b(x0[i]); o[4 + i] = f2b(x1[i]); }
    *(us8*)(dst + off) = o;
  } else {
    // ---- LN1: f32 -> bf16, one wave per row ----
    const int row  = (blk - 3584) * 4 + (tid >> 6);
    const int lane = tid & 63;
    const float* xr = x + (size_t)row * DM_ + lane * 8;
    f32x4 x0 = *(const f32x4*)xr;
    f32x4 x1 = *(const f32x4*)(xr + 4);
    float v[8]; float s = 0.f;
#pragma unroll
    for (int i = 0; i < 4; i++) { v[i] = x0[i]; v[4 + i] = x1[i]; }
#pragma unroll
    for (int i = 0; i < 8; i++) s += v[i];
#pragma unroll
    for (int o = 1; o < 64; o <<= 1) s += __shfl_xor(s, o);
    const float mu = s * (1.f / DM_);
    float q = 0.f;
#pragma unroll
    for (int i = 0; i < 8; i++) { float d = v[i] - mu; q += d * d; }
#pragma unroll
    for (int o = 1; o < 64; o <<= 1) q += __shfl_xor(q, o);
    const float rstd = rsqrtf(q * (1.f / DM_) + 1e-5f);
    f32x4 w0 = *(const f32x4*)(lw + lane * 8);
    f32x4 w1 = *(const f32x4*)(lw + lane * 8 + 4);
    f32x4 b0 = *(const f32x4*)(lb + lane * 8);
    f32x4 b1 = *(const f32x4*)(lb + lane * 8 + 4);
    us8 out;
#pragma unroll
    for (int i = 0; i < 4; i++) {
      out[i]     = f2b((v[i] - mu) * rstd * w0[i] + b0[i]);
      out[4 + i] = f2b((v[4 + i] - mu) * rstd * w1[i] + b1[i]);
    }
    *(us8*)(y + (size_t)row * DM_ + lane * 8) = out;
  }
}

// ---------------- LayerNorm (bf16 in, bf16 out): one wave per row of 512 ----------------
__global__ __launch_bounds__(256) void ln_kernel(const unsigned short* __restrict__ x,
                                                 const float* __restrict__ w,
                                                 const float* __restrict__ b,
                                                 unsigned short* __restrict__ y) {
  const int row  = blockIdx.x * 4 + (threadIdx.x >> 6);
  const int lane = threadIdx.x & 63;
  us8 raw = *(const us8*)(x + (size_t)row * DM_ + lane * 8);
  float v[8]; float s = 0.f;
#pragma unroll
  for (int i = 0; i < 8; i++) { v[i] = b2f(raw[i]); s += v[i]; }
#pragma unroll
  for (int o = 1; o < 64; o <<= 1) s += __shfl_xor(s, o);
  const float mu = s * (1.f / DM_);
  float q = 0.f;
#pragma unroll
  for (int i = 0; i < 8; i++) { float d = v[i] - mu; q += d * d; }
#pragma unroll
  for (int o = 1; o < 64; o <<= 1) q += __shfl_xor(q, o);
  const float rstd = rsqrtf(q * (1.f / DM_) + 1e-5f);
  f32x4 w0 = *(const f32x4*)(w + lane * 8);
  f32x4 w1 = *(const f32x4*)(w + lane * 8 + 4);
  f32x4 b0 = *(const f32x4*)(b + lane * 8);
  f32x4 b1 = *(const f32x4*)(b + lane * 8 + 4);
  us8 out;
#pragma unroll
  for (int i = 0; i < 4; i++) {
    out[i]     = f2b((v[i] - mu) * rstd * w0[i] + b0[i]);
    out[4 + i] = f2b((v[4 + i] - mu) * rstd * w1[i] + b1[i]);
  }
  *(us8*)(y + (size_t)row * DM_ + lane * 8) = out;
}

// ---------------- GEMM: C = A(MxK,bf16) * B(NxK,bf16)^T, 128xTN tile, BK=32 ----------------
// 2-phase double-buffered LDS pipeline; R9-exact epilogue; 4-chunk XOR source
// swizzle (bank conflicts = 0, R14-verified). Residual stream stored bf16.
struct GemmP {
  const unsigned short* A;
  const unsigned short* Bw;
  const float* bias;
  const float* residf;          // f32 resid (o-proj reads input Z)
  const unsigned short* residb; // bf16 resid (FFN2 reads bufZb)
  unsigned short* outb;
  float* outf;
  unsigned short* out_q;
  unsigned short* out_k;
  int K;
  int tiles_n;
  int ldo;
};

// EPI: 0=QKV scatter(bf16), 1=+resid(f32)->bf16, 2=relu(+bias)->bf16, 3=+bias+resid(bf16)->f32
template <int EPI, int TN>
__global__ __launch_bounds__(256) void gemm_bt(GemmP p) {
  constexpr int NFR = TN / 32;  // n-frags per wave
  __shared__ unsigned short As[2][128 * 32];
  __shared__ unsigned short Bs[2][TN * 32];
  const int tid = threadIdx.x;
  const int wave = tid >> 6, lane = tid & 63;
  const int wm = wave >> 1, wn = wave & 1;
  const int bid = xcd_swz(blockIdx.x, gridDim.x);
  const int tn = bid % p.tiles_n, tm = bid / p.tiles_n;
  const int K = p.K;
  const unsigned short* Ab = p.A + (size_t)tm * 128 * K;
  const unsigned short* Bb = p.Bw + (size_t)tn * TN * K;
  f32x4 acc[4][NFR];
#pragma unroll
  for (int i = 0; i < 4; i++)
#pragma unroll
    for (int j = 0; j < NFR; j++) acc[i][j] = (f32x4){0.f, 0.f, 0.f, 0.f};

  const int l15 = lane & 15;
  const int srow = lane >> 2;
  const int scol = (((lane & 3) ^ ((srow >> 1) & 3))) * 8;  // source-swizzled chunk
  auto stage = [&](int buf, int kt) {
#pragma unroll
    for (int i = 0; i < 2; i++) {
      const int r = wave * 32 + i * 16;
      gld_lds16(Ab + (size_t)(r + srow) * K + kt + scol, &As[buf][r * 32]);
    }
    if (TN == 128) {
#pragma unroll
      for (int i = 0; i < 2; i++) {
        const int r = wave * 32 + i * 16;
        gld_lds16(Bb + (size_t)(r + srow) * K + kt + scol, &Bs[buf][r * 32]);
      }
    } else {
      const int r = wave * 16;
      gld_lds16(Bb + (size_t)(r + srow) * K + kt + scol, &Bs[buf][r * 32]);
    }
  };

  stage(0, 0);
  __syncthreads();  // buf0 ready
  const int nIter = K >> 5;
  const int rchunk = (((lane >> 4) ^ ((l15 >> 1) & 3))) * 8;  // swizzled read slot
  for (int it = 0; it < nIter; it++) {
    const int buf = it & 1;
    if (it + 1 < nIter) stage(buf ^ 1, (it + 1) * 32);  // overlap with compute
    bf16x8 af[4], bfr[NFR];
#pragma unroll
    for (int m = 0; m < 4; m++)
      af[m] = *(const bf16x8*)&As[buf][(wm * 64 + m * 16 + l15) * 32 + rchunk];
#pragma unroll
    for (int n = 0; n < NFR; n++)
      bfr[n] = *(const bf16x8*)&Bs[buf][(wn * (TN / 2) + n * 16 + l15) * 32 + rchunk];
#pragma unroll
    for (int m = 0; m < 4; m++)
#pragma unroll
      for (int n = 0; n < NFR; n++)
        acc[m][n] = __builtin_amdgcn_mfma_f32_16x16x32_bf16(af[m], bfr[n], acc[m][n], 0, 0, 0);
    __syncthreads();  // next buf staged + all waves done reading this buf
  }

  const int r0 = tm * 128 + wm * 64;
  const int c0 = tn * TN + wn * (TN / 2);
#pragma unroll
  for (int m = 0; m < 4; m++) {
#pragma unroll
    for (int n = 0; n < NFR; n++) {
#pragma unroll
      for (int rr = 0; rr < 4; rr++) {
        const int row = r0 + m * 16 + (lane >> 4) * 4 + rr;
        const int col = c0 + n * 16 + (lane & 15);
        float v = acc[m][n][rr];
        if (EPI == 0) {
          v += p.bias[col];
          const int h = col / 192, j = col % 192;
          const int bb = row >> 9, nn = row & 511;
          const size_t base = (((size_t)bb * H_ + h) * N_ + nn) * DH_;
          if (j < 64)       p.outb [base + j]        = f2b(v);            // V
          else if (j < 128) p.out_q[base + j - 64]   = f2b(v * 0.125f);   // Q (scale folded)
          else              p.out_k[base + j - 128]  = f2b(v);            // K
        } else if (EPI == 1) {
          p.outb[(size_t)row * p.ldo + col] =
              f2b(v + p.residf[(size_t)row * p.ldo + col]);
        } else if (EPI == 2) {
          v += p.bias[col];
          v = v > 0.f ? v : 0.f;
          p.outb[(size_t)row * p.ldo + col] = f2b(v);
        } else {
          p.outf[(size_t)row * p.ldo + col] =
              v + p.bias[col] + b2f(p.residb[(size_t)row * p.ldo + col]);
        }
      }
    }
  }
}

// ---------------- V transpose: V[b][h][n][d] -> Vt[b][h][d][n] (bf16) ----------------
__global__ __launch_bounds__(256) void transp_v(const unsigned short* __restrict__ V,
                                                unsigned short* __restrict__ Vt) {
  __shared__ unsigned short t[64][65];
  const int bid = blockIdx.x;
  const int bh = bid >> 3, nt = bid & 7;
  const int n0 = nt * 64;
  const int tid = threadIdx.x;
  const unsigned short* src = V + ((size_t)bh * N_ + n0) * DH_;
  {
    const int r = tid >> 2, c = (tid & 3) * 16;
    us8 a = *(const us8*)(src + (size_t)r * DH_ + c);
    us8 b8 = *(const us8*)(src + (size_t)r * DH_ + c + 8);
#pragma unroll
    for (int i = 0; i < 8; i++) { t[r][c + i] = a[i]; t[r][c + 8 + i] = b8[i]; }
  }
  __syncthreads();
  {
    const int d = tid >> 2, nc = (tid & 3) * 16;
    us8 o1, o2;
#pragma unroll
    for (int i = 0; i < 8; i++) { o1[i] = t[nc + i][d]; o2[i] = t[nc + 8 + i][d]; }
    unsigned short* dst = Vt + ((size_t)bh * DH_ + d) * N_ + n0 + nc;
    *(us8*)dst = o1;
    *(us8*)(dst + 8) = o2;
  }
}

// ---------------- Fused flash attention ----------------
__global__ __launch_bounds__(256, 3) void attn_kernel(
    const unsigned short* __restrict__ Qs, const unsigned short* __restrict__ Ks,
    const unsigned short* __restrict__ Vt, const unsigned int* __restrict__ packed,
    unsigned short* __restrict__ attn_out) {
  __shared__ unsigned short Kt[64 * 64];    // [ki][d], chunk-XOR-swizzled
  __shared__ unsigned short Vtt[64 * 64];   // [d][ki], chunk-XOR-swizzled

  const int bid = xcd_swz(blockIdx.x, gridDim.x);
  const int qt = bid & 7, h = (bid >> 3) & 7, b = bid >> 6;
  const int q0 = qt * 64;
  const int tid = threadIdx.x, wave = tid >> 6, lane = tid & 63;
  const int q = lane & 15, hi = lane >> 4;

  const int q_g = q0 + wave * 16 + q;  // this lane's q row
  const size_t bh = (size_t)b * H_ + h;
  const unsigned short* Qb = Qs + (bh * N_ + q_g) * DH_;
  bf16x8 qf[2];
  qf[0] = *(const bf16x8*)(Qb + hi * 8);
  qf[1] = *(const bf16x8*)(Qb + 32 + hi * 8);

  const unsigned short* Kb = Ks + bh * N_ * DH_;
  const unsigned short* Vb = Vt + bh * DH_ * N_;
  const unsigned int* Pbase = packed + (size_t)b * N_ * N_ + q_g;

  f32x4 o[4];
#pragma unroll
  for (int i = 0; i < 4; i++) o[i] = (f32x4){0.f, 0.f, 0.f, 0.f};
  float dsum = 0.f;

  const int str = tid >> 2;
  const int stc = tid & 3;

  us8 pk0, pk1, pv0, pv1;
  unsigned int ppw[16];

  auto load_tile = [&](int kt) {
    const unsigned short* Kp = Kb + (size_t)(kt + str) * DH_ + stc * 16;
    const unsigned short* Vp = Vb + (size_t)str * N_ + kt + stc * 16;
    pk0 = *(const us8*)Kp;
    pk1 = *(const us8*)(Kp + 8);
    pv0 = *(const us8*)Vp;
    pv1 = *(const us8*)(Vp + 8);
    const unsigned int* Pp = Pbase + (size_t)(kt + hi * 4) * N_;
#pragma unroll
    for (int c = 0; c < 4; c++)
#pragma unroll
      for (int j = 0; j < 4; j++)
        ppw[c * 4 + j] = Pp[(size_t)(c * 16 + j) * N_];
  };

  load_tile(0);

  for (int kt = 0; kt < N_; kt += 64) {
    __syncthreads();  // all waves done reading previous tile's LDS
    {
      const int c0 = (stc * 2) ^ (str & 7);
      const int c1 = (stc * 2 + 1) ^ (str & 7);
      *(us8*)&Kt[str * 64 + c0 * 8] = pk0;
      *(us8*)&Kt[str * 64 + c1 * 8] = pk1;
      *(us8*)&Vtt[str * 64 + c0 * 8] = pv0;
      *(us8*)&Vtt[str * 64 + c1 * 8] = pv1;
    }
    unsigned int cpw[16];
#pragma unroll
    for (int i = 0; i < 16; i++) cpw[i] = ppw[i];
    __syncthreads();
    if (kt + 64 < N_) load_tile(kt + 64);

    // --- S^T = K * Q^T (Q pre-scaled by 1/8): C[ki][q], col=q, row=hi*4+r ---
    f32x4 s4[4];
#pragma unroll
    for (int c = 0; c < 4; c++) {
      f32x4 a = (f32x4){0.f, 0.f, 0.f, 0.f};
#pragma unroll
      for (int kd = 0; kd < 2; kd++) {
        const int krow = c * 16 + q;
        const int chunk = (kd * 4 + hi) ^ (q & 7);
        bf16x8 kf = *(const bf16x8*)&Kt[krow * 64 + chunk * 8];
        a = __builtin_amdgcn_mfma_f32_16x16x32_bf16(kf, qf[kd], a, 0, 0, 0);
      }
      s4[c] = a;
    }

    // --- softmax: pj = exp(s)*E (denominator), pm = exp(s)*Em (numerator) ---
    unsigned int pkk[4][2];
#pragma unroll
    for (int c = 0; c < 4; c++) {
      float pm[4];
#pragma unroll
      for (int r = 0; r < 4; r++) {
        const float es = __expf(s4[c][r]);
        const unsigned int w = cpw[c * 4 + r];
        dsum += es * b2f((unsigned short)(w & 0xffffu));
        pm[r] = es * b2f((unsigned short)(w >> 16));
      }
      pkk[c][0] = (unsigned int)f2b(pm[0]) | ((unsigned int)f2b(pm[1]) << 16);
      pkk[c][1] = (unsigned int)f2b(pm[2]) | ((unsigned int)f2b(pm[3]) << 16);
    }

    // --- O^T += V^T * P^T : A=Vt rows (lane-local), B=P (registers) ---
#pragma unroll
    for (int dc = 0; dc < 4; dc++) {
      const int vrow = dc * 16 + q;
#pragma unroll
      for (int t = 0; t < 2; t++) {
        u32x4 pb = {pkk[t][0], pkk[t][1], pkk[t + 2][0], pkk[t + 2][1]};
        bf16x8 pf = __builtin_bit_cast(bf16x8, pb);
        const int ch1 = (2 * t + (hi >> 1)) ^ (vrow & 7);
        const int ch2 = (2 * t + 4 + (hi >> 1)) ^ (vrow & 7);
        us4 v1 = *(const us4*)&Vtt[vrow * 64 + ch1 * 8 + (hi & 1) * 4];
        us4 v2 = *(const us4*)&Vtt[vrow * 64 + ch2 * 8 + (hi & 1) * 4];
        us8 vv;
#pragma unroll
        for (int i = 0; i < 4; i++) { vv[i] = v1[i]; vv[4 + i] = v2[i]; }
        bf16x8 vf = __builtin_bit_cast(bf16x8, vv);
        o[dc] = __builtin_amdgcn_mfma_f32_16x16x32_bf16(vf, pf, o[dc], 0, 0, 0);
      }
    }
  }

  // denominator: sum across the 4 hi-groups sharing this q
  dsum += __shfl_xor(dsum, 16);
  dsum += __shfl_xor(dsum, 32);
  const float inv = 1.f / dsum;

  const size_t obase = ((size_t)b * N_ + q_g) * DM_ + h * DH_ + hi * 4;
#pragma unroll
  for (int dc = 0; dc < 4; dc++) {
    us4 ov;
#pragma unroll
    for (int r = 0; r < 4; r++) {
      float val = o[dc][r] * inv;
      val = val >= 0.f ? val : 0.01f * val;  // leaky_relu fused
      ov[r] = f2b(val);
    }
    *(us4*)&attn_out[obase + dc * 16] = ov;
  }
}

extern "C" void kernel_launch(void* const* d_in, const int* in_sizes, int n_in,
                              void* d_out, int out_size, void* d_ws, size_t ws_size,
                              hipStream_t stream) {
  const float* Z     = (const float*)d_in[0];
  const float* D     = (const float*)d_in[1];
  const float* nm    = (const float*)d_in[2];
  const float* mask  = (const float*)d_in[3];
  const float* gamma = (const float*)d_in[4];
  const float* qkv_w = (const float*)d_in[5];
  const float* qkv_b = (const float*)d_in[6];
  const float* o_w   = (const float*)d_in[7];
  const float* ln1_w = (const float*)d_in[8];
  const float* ln1_b = (const float*)d_in[9];
  const float* ln2_w = (const float*)d_in[10];
  const float* ln2_b = (const float*)d_in[11];
  const float* p1_w  = (const float*)d_in[12];
  const float* p1_b  = (const float*)d_in[13];
  const float* p2_w  = (const float*)d_in[14];
  const float* p2_b  = (const float*)d_in[15];
  const int* ra = (const int*)d_in[16];
  const int* rb = (const int*)d_in[17];
  float* out = (float*)d_out;

  const size_t SZ = (size_t)16384 * 512;  // elements per (B*N, DM) buffer
  unsigned short* buf0  = (unsigned short*)d_ws;  // Zn -> attn_act -> Zn2 (bf16)
  unsigned short* bufQ  = buf0 + SZ;
  unsigned short* bufK  = bufQ + SZ;
  unsigned short* bufV  = bufK + SZ;
  unsigned short* bufVt = bufV + SZ;
  float* bufZspan = (float*)(bufVt + SZ);         // SZ floats span
  unsigned short* bufZb = (unsigned short*)bufZspan;  // residual stream (bf16)
  unsigned short* bufH = bufQ;                    // FFN hidden reuses Q/K/V/Vt span
  unsigned int* packed = (unsigned int*)bufZspan; // packed E/Em reuses span (consumed
                                                  // by attn before o-proj writes bufZb)
  unsigned short* wQKV = (unsigned short*)(bufZspan + SZ);
  unsigned short* wO   = wQKV + (size_t)3 * DM_ * DM_;
  unsigned short* wP1  = wO + (size_t)DM_ * DM_;
  unsigned short* wP2  = wP1 + (size_t)DI_ * DM_;

  // 0. fused prologue: prep_sm (2048) + conv_w (1536) + LN1 (4096)
  fused_pre<<<7680, 256, 0, stream>>>(D, nm, mask, gamma, ra, rb, packed,
                                      qkv_w, o_w, p1_w, p2_w, wQKV, wO, wP1, wP2,
                                      Z, ln1_w, ln1_b, buf0);

  // 2. QKV projection (TM=128, TN=64, grid 3072)
  GemmP p1{};
  p1.A = buf0; p1.Bw = wQKV; p1.bias = qkv_b;
  p1.outb = bufV; p1.out_q = bufQ; p1.out_k = bufK;
  p1.K = 512; p1.tiles_n = 24; p1.ldo = 0;
  gemm_bt<0, 64><<<128 * 24, 256, 0, stream>>>(p1);

  // 3. V transpose
  transp_v<<<2048, 256, 0, stream>>>(bufV, bufVt);

  // 4. Fused attention (incl. leaky_relu)
  attn_kernel<<<B_ * H_ * 8, 256, 0, stream>>>(bufQ, bufK, bufVt, packed, buf0);

  // 5. Output projection + residual -> bf16 (TN=64, grid 1024)
  GemmP p3{};
  p3.A = buf0; p3.Bw = wO; p3.residf = Z; p3.outb = bufZb;
  p3.K = 512; p3.tiles_n = 8; p3.ldo = 512;
  gemm_bt<1, 64><<<128 * 8, 256, 0, stream>>>(p3);

  // 6. LN2 (bf16 -> bf16)
  ln_kernel<<<4096, 256, 0, stream>>>(bufZb, ln2_w, ln2_b, buf0);

  // 7. FFN up + relu (TN=128, grid 2048)
  GemmP p5{};
  p5.A = buf0; p5.Bw = wP1; p5.bias = p1_b; p5.outb = bufH;
  p5.K = 512; p5.tiles_n = 16; p5.ldo = 2048;
  gemm_bt<2, 128><<<128 * 16, 256, 0, stream>>>(p5);

  // 8. FFN down + bias + resid(bf16) -> out (f32) (TN=64, grid 1024)
  GemmP p6{};
  p6.A = bufH; p6.Bw = wP2; p6.bias = p2_b; p6.residb = bufZb; p6.outf = out;
  p6.K = 2048; p6.tiles_n = 8; p6.ldo = 512;
  gemm_bt<3, 64><<<128 * 8, 256, 0, stream>>>(p6);
}